// Round 5
// baseline (768.445 us; speedup 1.0000x reference)
//
#include <hip/hip_runtime.h>
#include <math.h>

#define Bq    128
#define Dq    128
#define Hq    50
#define NEGq  4
#define Lq    30
#define Sq    55      // H + 1 + NEG
#define NPGq  80
#define Nq    10240   // B * NPG
#define Eq    163840  // N * 16
#define NEWSq 7040    // B * S
#define BEq   28160   // NEWS * 4
#define WVOCq 50000
#define NEG1q 5

__device__ __forceinline__ float leaky_f(float x) { return x > 0.f ? x : 0.2f * x; }

// ---------------------------------------------------------------- CSR build (fused x3)
__global__ void k_count_all(const int* __restrict__ ei_dst, const int* __restrict__ bi_node,
                            const int* __restrict__ bi_news,
                            int* __restrict__ cg, int* __restrict__ cbn, int* __restrict__ cbw) {
    int e = blockIdx.x * blockDim.x + threadIdx.x;
    if (e < Eq) atomicAdd(&cg[ei_dst[e]], 1);
    else if (e < Eq + BEq) atomicAdd(&cbn[bi_node[e - Eq]], 1);
    else if (e < Eq + 2 * BEq) atomicAdd(&cbw[bi_news[e - Eq - BEq]], 1);
}

__global__ __launch_bounds__(1024) void k_scan3(
        const int* __restrict__ cg, const int* __restrict__ cbn, const int* __restrict__ cbw,
        int* __restrict__ og, int* __restrict__ obn, int* __restrict__ obw,
        int* __restrict__ curg, int* __restrict__ curbn, int* __restrict__ curbw) {
    __shared__ int part[1024];
    const int* cnt; int* off; int* cur; int n;
    if (blockIdx.x == 0)      { cnt = cg;  off = og;  cur = curg;  n = Nq; }
    else if (blockIdx.x == 1) { cnt = cbn; off = obn; cur = curbn; n = Nq; }
    else                      { cnt = cbw; off = obw; cur = curbw; n = NEWSq; }
    int tid = threadIdx.x;
    int chunk = (n + 1023) >> 10;
    int s0 = tid * chunk;
    int s1 = s0 + chunk; if (s1 > n) s1 = n;
    int s = 0;
    for (int i = s0; i < s1; ++i) s += cnt[i];
    part[tid] = s;
    __syncthreads();
    for (int d = 1; d < 1024; d <<= 1) {
        int v = (tid >= d) ? part[tid - d] : 0;
        __syncthreads();
        part[tid] += v;
        __syncthreads();
    }
    int base = (tid > 0) ? part[tid - 1] : 0;
    for (int i = s0; i < s1; ++i) { off[i] = base; cur[i] = base; base += cnt[i]; }
    if (tid == 0) off[n] = part[1023];
}

__global__ void k_scatter_all(const int* __restrict__ ei_src, const int* __restrict__ ei_dst,
                              const int* __restrict__ bi_news, const int* __restrict__ bi_node,
                              int* __restrict__ curg, int* __restrict__ curbn, int* __restrict__ curbw,
                              int* __restrict__ g_out, int* __restrict__ bn_out, int* __restrict__ bw_out) {
    int e = blockIdx.x * blockDim.x + threadIdx.x;
    if (e < Eq) {
        int slot = atomicAdd(&curg[ei_dst[e]], 1);
        g_out[slot] = ei_src[e];
    } else if (e < Eq + BEq) {
        int i = e - Eq;
        int slot = atomicAdd(&curbn[bi_node[i]], 1);
        bn_out[slot] = bi_news[i];
    } else if (e < Eq + 2 * BEq) {
        int i = e - Eq - BEq;
        int slot = atomicAdd(&curbw[bi_news[i]], 1);
        bw_out[slot] = bi_node[i];
    }
}

// ---------------------------------------------------------------- gathers
__global__ void k_embed(const int* __restrict__ nodes, const float* __restrict__ ent,
                        float* __restrict__ out, int n) {
    int i = blockIdx.x * blockDim.x + threadIdx.x;
    if (i < n * 32) {
        int r = i >> 5, d = i & 31;
        ((float4*)out)[i] = ((const float4*)(ent + (long)nodes[r] * 128))[d];
    }
}

// ---------------------------------------------------------------- matmul core
// Tile: 64 rows x 128 cols, 256 threads, 8x4 micro-tile (6 ds_read_b128 / 64 MAC).
// f32 FMA chains over 16-deep k-chunks, f64 merge every 16 k.
// K staged in 4 slices of 32 -> LDS = 16KB(W) + 8KB(A) = 24KB.
// amap=1: A row r maps to user slot (r/50)*55 + r%50 (NC gather).
#define MMROWS 64

#define MM4(RR, CC, WC) \
    f[RR][CC] = fmaf(a.x, w0.WC, f[RR][CC]); \
    f[RR][CC] = fmaf(a.y, w1.WC, f[RR][CC]); \
    f[RR][CC] = fmaf(a.z, w2.WC, f[RR][CC]); \
    f[RR][CC] = fmaf(a.w, w3.WC, f[RR][CC]);

__device__ __forceinline__ void mm_compute(float* sW, float (*sA)[32],
        const float* __restrict__ A, const float* __restrict__ W,
        int M, int r0, int amap, double acc[8][4]) {
    int tid = threadIdx.x;
    int tx = tid & 31;                    // col group -> j0 = tx*4
    int ty = tid >> 5;                    // row group -> rows ty*8 .. ty*8+7
    int j0 = tx * 4;
#pragma unroll
    for (int rr = 0; rr < 8; ++rr)
#pragma unroll
        for (int cc = 0; cc < 4; ++cc) acc[rr][cc] = 0.0;

    for (int ks = 0; ks < 4; ++ks) {
        __syncthreads();
        const float4* W4 = (const float4*)(W + ks * 32 * 128);
        float4* sW4 = (float4*)sW;
#pragma unroll
        for (int i = tid; i < 32 * 32; i += 256) sW4[i] = W4[i];
#pragma unroll
        for (int i = tid; i < MMROWS * 8; i += 256) {   // 64 rows x 8 float4
            int r = i >> 3, c4 = i & 7;
            int gr = r0 + r;
            float4 v = make_float4(0.f, 0.f, 0.f, 0.f);
            if (gr < M) {
                long pr = amap ? (long)((gr / Hq) * Sq + gr % Hq) : (long)gr;
                v = *(const float4*)(A + pr * 128 + ks * 32 + c4 * 4);
            }
            *(float4*)&sA[r][c4 * 4] = v;
        }
        __syncthreads();
#pragma unroll
        for (int half = 0; half < 2; ++half) {
            float f[8][4];
#pragma unroll
            for (int rr = 0; rr < 8; ++rr)
#pragma unroll
                for (int cc = 0; cc < 4; ++cc) f[rr][cc] = 0.f;
#pragma unroll
            for (int k4 = 0; k4 < 16; k4 += 4) {
                int k = half * 16 + k4;
                float4 w0 = *(const float4*)&sW[(k + 0) * 128 + j0];
                float4 w1 = *(const float4*)&sW[(k + 1) * 128 + j0];
                float4 w2 = *(const float4*)&sW[(k + 2) * 128 + j0];
                float4 w3 = *(const float4*)&sW[(k + 3) * 128 + j0];
#pragma unroll
                for (int rr = 0; rr < 8; ++rr) {
                    float4 a = *(const float4*)&sA[ty * 8 + rr][k];
                    MM4(rr, 0, x) MM4(rr, 1, y) MM4(rr, 2, z) MM4(rr, 3, w)
                }
            }
#pragma unroll
            for (int rr = 0; rr < 8; ++rr)
#pragma unroll
                for (int cc = 0; cc < 4; ++cc) acc[rr][cc] += (double)f[rr][cc];
        }
    }
}

// ---- generic job-table matmul: C store (opt) + row dots (opt, 1 or 2)
struct MMJob {
    const float* A; const float* W; float* C;
    const float* q0; const float* q1;
    float* o0; float* o1;
    int M; int blk_end; int amap;
};
struct MMJobs { MMJob j[4]; };

__global__ __launch_bounds__(256) void k_mm_jobs(MMJobs js) {
    __shared__ float sW[32 * 128];
    __shared__ float sA[MMROWS][32];
    int bid = blockIdx.x;
    int ji = 0, blk0 = 0;
#pragma unroll
    for (int t = 0; t < 3; ++t)
        if (bid >= js.j[t].blk_end) { ji = t + 1; blk0 = js.j[t].blk_end; }
    MMJob J = js.j[ji];
    double acc[8][4];
    int r0 = (bid - blk0) * MMROWS;
    mm_compute(sW, sA, J.A, J.W, J.M, r0, J.amap, acc);
    int tid = threadIdx.x, tx = tid & 31, ty = tid >> 5;
    int j0 = tx * 4;
    if (J.C) {
#pragma unroll
        for (int rr = 0; rr < 8; ++rr) {
            int r = r0 + ty * 8 + rr;
            if (r < J.M) {
                float4 o = make_float4((float)acc[rr][0], (float)acc[rr][1],
                                       (float)acc[rr][2], (float)acc[rr][3]);
                *(float4*)&J.C[(long)r * 128 + j0] = o;
            }
        }
    }
    if (J.o0) {
        float q0c[4], q1c[4];
        bool two = (J.q1 != nullptr);
#pragma unroll
        for (int cc = 0; cc < 4; ++cc) {
            q0c[cc] = J.q0[j0 + cc];
            q1c[cc] = two ? J.q1[j0 + cc] : 0.f;
        }
#pragma unroll
        for (int rr = 0; rr < 8; ++rr) {
            int r = r0 + ty * 8 + rr;
            double d0 = 0.0, d1 = 0.0;
#pragma unroll
            for (int cc = 0; cc < 4; ++cc) {
                double c = (double)(float)acc[rr][cc];   // f32-rounded C
                d0 += c * (double)q0c[cc];
                d1 += c * (double)q1c[cc];
            }
            for (int o = 16; o > 0; o >>= 1) {
                d0 += __shfl_xor(d0, o);
                if (two) d1 += __shfl_xor(d1, o);
            }
            if ((tid & 31) == 0 && r < J.M) {
                J.o0[r] = (float)d0;
                if (two) J.o1[r] = (float)d1;
            }
        }
    }
}

// ---- tanh-dot matmul: o0[r] = sum_j tanh(C[r][j]+q0[j])*q1[j]  (no C store)
__global__ __launch_bounds__(256) void k_mm_tanh(const float* __restrict__ A,
        const float* __restrict__ W, int M,
        const float* __restrict__ q0, const float* __restrict__ q1,
        float* __restrict__ o0) {
    __shared__ float sW[32 * 128];
    __shared__ float sA[MMROWS][32];
    double acc[8][4];
    int r0 = blockIdx.x * MMROWS;
    mm_compute(sW, sA, A, W, M, r0, 0, acc);
    int tid = threadIdx.x, tx = tid & 31, ty = tid >> 5;
    int j0 = tx * 4;
    float q0c[4], q1c[4];
#pragma unroll
    for (int cc = 0; cc < 4; ++cc) { q0c[cc] = q0[j0 + cc]; q1c[cc] = q1[j0 + cc]; }
#pragma unroll
    for (int rr = 0; rr < 8; ++rr) {
        int r = r0 + ty * 8 + rr;
        double s = 0.0;
#pragma unroll
        for (int cc = 0; cc < 4; ++cc) {
            float t = (float)acc[rr][cc] + q0c[cc];
            s += (double)tanhf(t) * (double)q1c[cc];
        }
        for (int o = 16; o > 0; o >>= 1) s += __shfl_xor(s, o);
        if ((tid & 31) == 0 && r < M) o0[r] = (float)s;
    }
}

// ---------------------------------------------------------------- title pooling
__global__ __launch_bounds__(128) void k_title_pool(
        const int* __restrict__ title_tok, const float* __restrict__ wscore,
        const float* __restrict__ wemb,
        const int* __restrict__ hist_seqs, const int* __restrict__ hist_lens,
        const int* __restrict__ pos_seq, const int* __restrict__ pos_len,
        const int* __restrict__ neg_seqs, const int* __restrict__ neg_lens,
        float* __restrict__ UTraw, float* __restrict__ news1) {
    int t = blockIdx.x;
    int b = t / Sq, s = t % Sq;
    int nid, len; float* dst;
    if (s < Hq)       { nid = hist_seqs[b * Hq + s]; len = hist_lens[b * Hq + s]; dst = UTraw + (long)(b * Hq + s) * 128; }
    else if (s == Hq) { nid = pos_seq[b];            len = pos_len[b];            dst = news1 + (long)t * 128; }
    else { int g = s - Hq - 1; nid = neg_seqs[b * NEGq + g]; len = neg_lens[b * NEGq + g]; dst = news1 + (long)t * 128; }

    __shared__ int tok[Lq];
    __shared__ float wgt[Lq];
    __shared__ double sden;
    int tid = threadIdx.x;
    if (tid < Lq) tok[tid] = title_tok[(long)nid * Lq + tid];
    __syncthreads();
    if (tid < 64) {   // first wave does the softmax over len<=30 lanes
        float sc = (tid < len) ? wscore[tok[tid]] : -1e30f;
        float mx = sc;
        for (int o = 32; o > 0; o >>= 1) mx = fmaxf(mx, __shfl_xor(mx, o));
        float e = (tid < len) ? (float)exp((double)(sc - mx)) : 0.f;
        if (tid < Lq) wgt[tid] = e;
        double ds = (double)e;
        for (int o = 32; o > 0; o >>= 1) ds += __shfl_xor(ds, o);
        if (tid == 0) sden = ds;
    }
    __syncthreads();
    double den = sden;
    double acc = 0.0;
    for (int l = 0; l < len; ++l)
        acc += (double)wgt[l] * (double)wemb[(long)tok[l] * 128 + tid];
    dst[tid] = (float)(acc / den);
}

// ---------------------------------------------------------------- edge aggregation: wave per segment
#define WMAXK 128
struct EASet {
    const int* off; const int* srcs;
    const float* es; const float* ed;
    const float* Hsrc; const float* Xdst;
    float* Out; int nseg; int mode;
};

__global__ __launch_bounds__(256) void k_edge_agg_w(EASet a, EASet b,
        const float* __restrict__ gW, const float* __restrict__ gb, float* __restrict__ gout) {
    __shared__ int   sSrc[4][WMAXK];
    __shared__ float sE[4][WMAXK];
    int wv = threadIdx.x >> 6, lane = threadIdx.x & 63;
    int g = blockIdx.x * 4 + wv;
    if (g >= a.nseg + b.nseg) return;
    bool isA = g < a.nseg;
    EASet S = isA ? a : b;
    int n = isA ? g : g - a.nseg;
    int s0 = S.off[n], k = S.off[n + 1] - s0;
    int d0 = lane * 2;
    float o0, o1;
    if (k == 0) {
        if (S.mode) { float2 x = *(const float2*)&S.Xdst[(long)n * 128 + d0]; o0 = x.x; o1 = x.y; }
        else { o0 = 0.f; o1 = 0.f; }   // elu(0)=0
    } else {
        float edn = S.ed[n];
        float mloc = -1e30f;
        for (int j = lane; j < k; j += 64) {
            int sidx = S.srcs[s0 + j];
            float e = leaky_f(S.es[sidx] + edn);
            if (j < WMAXK) { sSrc[wv][j] = sidx; sE[wv][j] = e; }
            mloc = fmaxf(mloc, e);
        }
        for (int o = 32; o > 0; o >>= 1) mloc = fmaxf(mloc, __shfl_xor(mloc, o));
        float m = mloc;
        double dloc = 0.0;
        for (int j = lane; j < k; j += 64) {
            float e = (j < WMAXK) ? sE[wv][j] : leaky_f(S.es[S.srcs[s0 + j]] + edn);
            float ex = (float)exp((double)(e - m));
            if (j < WMAXK) sE[wv][j] = ex;
            dloc += (double)ex;
        }
        for (int o = 32; o > 0; o >>= 1) dloc += __shfl_xor(dloc, o);
        double den = dloc + 1e-16;
        for (int j = lane; j < k && j < WMAXK; j += 64)
            sE[wv][j] = (float)((double)sE[wv][j] / den);     // alpha
        double a0 = 0.0, a1 = 0.0;
        for (int j = 0; j < k; ++j) {
            float alpha; int sidx;
            if (j < WMAXK) { alpha = sE[wv][j]; sidx = sSrc[wv][j]; }
            else {
                sidx = S.srcs[s0 + j];
                float e = leaky_f(S.es[sidx] + edn);
                float ex = (float)exp((double)(e - m));
                alpha = (float)((double)ex / den);
            }
            float2 h = *(const float2*)&S.Hsrc[(long)sidx * 128 + d0];
            a0 += (double)alpha * (double)h.x;
            a1 += (double)alpha * (double)h.y;
        }
        float v0f = (float)a0, v1f = (float)a1;
        o0 = (v0f > 0.f) ? v0f : (float)expm1((double)v0f);
        o1 = (v1f > 0.f) ? v1f : (float)expm1((double)v1f);
        if (S.mode) {
            float2 x = *(const float2*)&S.Xdst[(long)n * 128 + d0];
            o0 += x.x; o1 += x.y;
        }
    }
    *(float2*)&S.Out[(long)n * 128 + d0] = make_float2(o0, o1);
    if (isA && gout) {   // fused gate = f32(dot(out_row, gW)) + gb
        double part = (double)o0 * (double)gW[d0] + (double)o1 * (double)gW[d0 + 1];
        for (int o = 32; o > 0; o >>= 1) part += __shfl_xor(part, o);
        if (lane == 0) gout[n] = (float)part + gb[0];
    }
}

// ---------------------------------------------------------------- self-attention (flat-parallel, one block per batch)
__global__ __launch_bounds__(256) void k_self_attn(const float* __restrict__ Q, const float* __restrict__ K,
                                                   const float* __restrict__ V, float* __restrict__ Out,
                                                   int ob_stride, const float* __restrict__ tail_src) {
    __shared__ float sQ[Hq][129];
    __shared__ float sK[Hq][129];
    __shared__ float sV[Hq * 128];
    __shared__ float sEx[Hq][52];
    __shared__ double sInv[Hq];
    const double SQRTD = (double)11.3137085f;  // f32(sqrt(128))
    int b = blockIdx.x;
    int tid = threadIdx.x;
    const float* Qb = Q + (long)b * Hq * 128;
    const float* Kb = K + (long)b * Hq * 128;
    const float* Vb = V + (long)b * Hq * 128;
    for (int idx = tid; idx < Hq * 128; idx += 256) {
        int r = idx >> 7, i = idx & 127;
        sQ[r][i] = Qb[idx];
        sK[r][i] = Kb[idx];
        sV[idx] = Vb[idx];
    }
    __syncthreads();
    // scores: each thread ~10 of the 2500 (r,j) dots (16-chunk f32, f64 merge)
    for (int p = tid; p < Hq * Hq; p += 256) {
        int r = p / Hq, j = p - r * Hq;
        double acc = 0.0;
#pragma unroll
        for (int c0 = 0; c0 < 128; c0 += 16) {
            float f = 0.f;
#pragma unroll
            for (int i = 0; i < 16; ++i) f = fmaf(sQ[r][c0 + i], sK[j][c0 + i], f);
            acc += (double)f;
        }
        sEx[r][j] = (float)(acc / SQRTD);
    }
    __syncthreads();
    // softmax: wave per row, shuffle reductions
    int wv = tid >> 6, lane = tid & 63;
    for (int r = wv; r < Hq; r += 4) {
        float s = (lane < Hq) ? sEx[r][lane] : -1e30f;
        float mx = s;
        for (int o = 32; o > 0; o >>= 1) mx = fmaxf(mx, __shfl_xor(mx, o));
        float ex = (lane < Hq) ? (float)exp((double)(s - mx)) : 0.f;
        double ds = (double)ex;
        for (int o = 32; o > 0; o >>= 1) ds += __shfl_xor(ds, o);
        if (lane < Hq) sEx[r][lane] = ex;
        if (lane == 0) sInv[r] = 1.0 / ds;
    }
    __syncthreads();
    // PV: each thread 25 (r,d) outputs
    int d = tid & 127, rh = tid >> 7;
    for (int r = rh; r < Hq; r += 2) {
        double acc = 0.0;
        for (int c0 = 0; c0 < Hq; c0 += 16) {
            float f = 0.f;
            int ce = (c0 + 16 < Hq) ? c0 + 16 : Hq;
            for (int c = c0; c < ce; ++c) f = fmaf(sEx[r][c], sV[c * 128 + d], f);
            acc += (double)f;
        }
        Out[(long)b * ob_stride + (long)r * 128 + d] = (float)(acc * sInv[r]);
    }
    // fold target-row copy (news2 <- NC1 tail)
    if (tail_src) {
        for (int idx = tid; idx < NEG1q * 128; idx += 256) {
            int rr = Hq + (idx >> 7), dd = idx & 127;
            Out[(long)b * ob_stride + (long)rr * 128 + dd] = tail_src[((long)(b * Sq + rr)) * 128 + dd];
        }
    }
}

// ---------------------------------------------------------------- masked pooling
__global__ __launch_bounds__(128) void k_mask_pool(const float* __restrict__ X, const float* __restrict__ gate,
        const int* __restrict__ hist_mask, const int* __restrict__ pos_mask, const int* __restrict__ neg_masks,
        float* __restrict__ pooled) {
    int blk = blockIdx.x;
    int b = blk / 6, s = blk % 6;
    int tid = threadIdx.x;
    __shared__ float sEx[NPGq];
    __shared__ float redf[128];
    __shared__ double redd[128];
    int base = b * NPGq;
    float logit = -1e30f; int mk = 0;
    if (tid < NPGq) {
        int n = base + tid;
        mk = (s == 0) ? hist_mask[n] : (s == 1) ? pos_mask[n] : neg_masks[n * NEGq + (s - 2)];
        logit = (mk > 0) ? gate[n] : -1000000000.0f;
    }
    redf[tid] = logit; __syncthreads();
    for (int d = 64; d > 0; d >>= 1) { if (tid < d) redf[tid] = fmaxf(redf[tid], redf[tid + d]); __syncthreads(); }
    float mx = redf[0];
    float ex = 0.f;
    if (tid < NPGq && mk > 0) ex = (float)exp((double)(logit - mx));
    if (tid < NPGq) sEx[tid] = ex;
    redd[tid] = (double)ex; __syncthreads();
    for (int d = 64; d > 0; d >>= 1) { if (tid < d) redd[tid] += redd[tid + d]; __syncthreads(); }
    double den = redd[0] + 1e-16;
    double acc = 0.0;
    for (int c0 = 0; c0 < NPGq; c0 += 16) {
        float f = 0.f;
#pragma unroll
        for (int c = 0; c < 16; ++c)
            f = fmaf(sEx[c0 + c], X[((long)(base + c0 + c)) * 128 + tid], f);
        acc += (double)f;
    }
    pooled[(long)blk * 128 + tid] = (float)(acc / den);
}

// ---------------------------------------------------------------- user final pool (softmax over H)
__global__ __launch_bounds__(128) void k_user_pool(const float* __restrict__ UT3, const float* __restrict__ score,
                                                   float* __restrict__ uvec) {
    int b = blockIdx.x, tid = threadIdx.x;
    __shared__ float sEx[Hq];
    __shared__ float redf[128];
    __shared__ double redd[128];
    float sv = (tid < Hq) ? score[b * Hq + tid] : -1e30f;
    redf[tid] = sv; __syncthreads();
    for (int d = 64; d > 0; d >>= 1) { if (tid < d) redf[tid] = fmaxf(redf[tid], redf[tid + d]); __syncthreads(); }
    float mx = redf[0];
    float ex = (tid < Hq) ? (float)exp((double)(sv - mx)) : 0.f;
    if (tid < Hq) sEx[tid] = ex;
    redd[tid] = (double)ex; __syncthreads();
    for (int d = 64; d > 0; d >>= 1) { if (tid < d) redd[tid] += redd[tid + d]; __syncthreads(); }
    double den = redd[0];
    double acc = 0.0;
    for (int h = 0; h < Hq; ++h)
        acc += (double)sEx[h] * (double)UT3[((long)(b * Hq + h)) * 128 + tid];
    uvec[(long)b * 128 + tid] = (float)(acc / den);
}

// ---------------------------------------------------------------- final gated score
__global__ __launch_bounds__(128) void k_final(const float* __restrict__ pooled, const float* __restrict__ uvec,
        const float* __restrict__ NC2, const float* __restrict__ wwW, const float* __restrict__ wwb,
        float* __restrict__ out) {
    int blk = blockIdx.x;
    int b = blk / NEG1q, g = blk % NEG1q;
    int tid = threadIdx.x;
    __shared__ double redd[128];
    const float* ug = pooled + (long)(b * 6 + 0) * 128;
    const float* tg = pooled + (long)(b * 6 + 1 + g) * 128;
    const float* ut = uvec + (long)b * 128;
    const float* tt = NC2 + (long)(b * Sq + Hq + g) * 128;
    double w0 = (double)wwW[tid], w1 = (double)wwW[128 + tid];

    redd[tid] = (double)ug[tid] * w0 + (double)ut[tid] * w1;
    __syncthreads();
    for (int d = 64; d > 0; d >>= 1) { if (tid < d) redd[tid] += redd[tid + d]; __syncthreads(); }
    float su = (float)redd[0] + wwb[0];
    float uwf = (float)(1.0 / (1.0 + exp(-(double)su)));
    __syncthreads();

    redd[tid] = (double)tg[tid] * w0 + (double)tt[tid] * w1;
    __syncthreads();
    for (int d = 64; d > 0; d >>= 1) { if (tid < d) redd[tid] += redd[tid + d]; __syncthreads(); }
    float st = (float)redd[0] + wwb[0];
    float twf = (float)(1.0 / (1.0 + exp(-(double)st)));
    __syncthreads();

    float uh = uwf * ug[tid] + (1.f - uwf) * ut[tid];
    float th = twf * tg[tid] + (1.f - twf) * tt[tid];
    redd[tid] = (double)uh * (double)th;
    __syncthreads();
    for (int d = 64; d > 0; d >>= 1) { if (tid < d) redd[tid] += redd[tid + d]; __syncthreads(); }
    if (tid == 0) out[blk] = (float)redd[0];
}

// ================================================================ launch
extern "C" void kernel_launch(void* const* d_in, const int* in_sizes, int n_in,
                              void* d_out, int out_size, void* d_ws, size_t ws_size,
                              hipStream_t stream) {
    // ---- inputs
    const int*   nodes      = (const int*)d_in[0];
    const int*   ei_src     = (const int*)d_in[1];
    const int*   ei_dst     = ei_src + Eq;
    const int*   bi_news    = (const int*)d_in[2];   // bi_edge_index[0]: news ids
    const int*   bi_node    = bi_news + BEq;         // bi_edge_index[1]: node ids
    const int*   hist_mask  = (const int*)d_in[4];
    const int*   pos_mask   = (const int*)d_in[5];
    const int*   neg_masks  = (const int*)d_in[6];
    const int*   hist_seqs  = (const int*)d_in[7];
    const int*   hist_lens  = (const int*)d_in[8];
    const int*   pos_seq    = (const int*)d_in[9];
    const int*   pos_len    = (const int*)d_in[10];
    const int*   neg_seqs   = (const int*)d_in[11];
    const int*   neg_lens   = (const int*)d_in[12];
    const int*   title_tok  = (const int*)d_in[13];
    const float* ent_emb    = (const float*)d_in[14];
    const float* word_emb   = (const float*)d_in[15];
    const float* te_W  = (const float*)d_in[16];
    const float* te_b  = (const float*)d_in[17];
    const float* te_v  = (const float*)d_in[18];
    const float* ue1_Wq = (const float*)d_in[19];
    const float* ue1_Wk = (const float*)d_in[20];
    const float* ue1_Wv = (const float*)d_in[21];
    const float* ue2_Wq = (const float*)d_in[22];
    const float* ue2_Wk = (const float*)d_in[23];
    const float* ue2_Wv = (const float*)d_in[24];
    const float* ue3_Wq = (const float*)d_in[25];
    const float* ue3_Wk = (const float*)d_in[26];
    const float* ue3_Wv = (const float*)d_in[27];
    const float* g1_W  = (const float*)d_in[28];
    const float* g1_as = (const float*)d_in[29];
    const float* g1_ad = (const float*)d_in[30];
    const float* g2_W  = (const float*)d_in[31];
    const float* g2_as = (const float*)d_in[32];
    const float* g2_ad = (const float*)d_in[33];
    const float* cg1_Ws = (const float*)d_in[34];
    const float* cg1_Wd = (const float*)d_in[35];
    const float* cg1_as = (const float*)d_in[36];
    const float* cg1_ad = (const float*)d_in[37];
    const float* cg2_Ws = (const float*)d_in[38];
    const float* cg2_Wd = (const float*)d_in[39];
    const float* cg2_as = (const float*)d_in[40];
    const float* cg2_ad = (const float*)d_in[41];
    const float* sa_W  = (const float*)d_in[42];
    const float* sa_b  = (const float*)d_in[43];
    const float* sa_v  = (const float*)d_in[44];
    const float* gate_W = (const float*)d_in[45];
    const float* gate_b = (const float*)d_in[46];
    const float* ww_W  = (const float*)d_in[47];
    const float* ww_b  = (const float*)d_in[48];
    float* out = (float*)d_out;

    // ---- workspace carve
    char* p = (char*)d_ws;
    auto alloc = [&](size_t bytes) -> void* {
        void* r = (void*)p;
        p += (bytes + 255) & ~(size_t)255;
        return r;
    };
    int* g_off  = (int*)alloc((Nq + 1) * 4);
    int* bn_off = (int*)alloc((Nq + 1) * 4);
    int* bw_off = (int*)alloc((NEWSq + 1) * 4);
    int* g_src  = (int*)alloc(Eq * 4);
    int* bn_src = (int*)alloc(BEq * 4);
    int* bw_src = (int*)alloc(BEq * 4);
    int* cnt3   = (int*)alloc((2 * Nq + NEWSq) * 4);   // cg | cbn | cbw contiguous
    int* cur3   = (int*)alloc((2 * Nq + NEWSq) * 4);
    int* cg  = cnt3, *cbn = cnt3 + Nq, *cbw = cnt3 + 2 * Nq;
    int* curg = cur3, *curbn = cur3 + Nq, *curbw = cur3 + 2 * Nq;

    float* wscore  = (float*)alloc(WVOCq * 4);
    float* UTraw   = (float*)alloc((size_t)Bq * Hq * 128 * 4);
    float* UT3     = (float*)alloc((size_t)Bq * Hq * 128 * 4);
    float* news1   = (float*)alloc((size_t)NEWSq * 128 * 4);
    float* NC1     = (float*)alloc((size_t)NEWSq * 128 * 4);
    float* news2   = (float*)alloc((size_t)NEWSq * 128 * 4);
    float* NC2     = (float*)alloc((size_t)NEWSq * 128 * 4);
    float* newsS1  = (float*)alloc((size_t)NEWSq * 128 * 4);   // vb / hs_news
    float* v0      = (float*)alloc((size_t)Nq * 128 * 4);
    float* v1      = (float*)alloc((size_t)Nq * 128 * 4);
    float* nc1     = (float*)alloc((size_t)Nq * 128 * 4);
    float* v2      = (float*)alloc((size_t)Nq * 128 * 4);
    float* nc2     = (float*)alloc((size_t)Nq * 128 * 4);
    float* nodeS1  = (float*)alloc((size_t)Nq * 128 * 4);      // qb / hs_node
    float* nodeS2  = (float*)alloc((size_t)Nq * 128 * 4);      // kb
    float* es_node = (float*)alloc(Nq * 4);
    float* ed_node = (float*)alloc(Nq * 4);
    float* es_news = (float*)alloc(NEWSq * 4);
    float* ed_news = (float*)alloc(NEWSq * 4);
    float* gate    = (float*)alloc(Nq * 4);
    float* score_bh = (float*)alloc(Bq * Hq * 4);
    float* user_vec = (float*)alloc(Bq * 128 * 4);
    float* pooled   = (float*)alloc((size_t)Bq * 6 * 128 * 4);

    float* qb = nodeS1;   // aliases (temporally disjoint)
    float* kb = nodeS2;
    float* vb = newsS1;

    const int MH = Bq * Hq;          // 6400
    const int nbMH   = (MH + MMROWS - 1) / MMROWS;      // 100
    const int nbNode = (Nq + MMROWS - 1) / MMROWS;      // 160
    const int nbNews = (NEWSq + MMROWS - 1) / MMROWS;   // 110
    const int nbWS   = (WVOCq + MMROWS - 1) / MMROWS;   // 782
    const int TOTE = Eq + 2 * BEq;
    const int BIG = 0x7fffffff;

    auto mkjob = [](const float* A, const float* W, float* C, const float* q0, const float* q1,
                    float* o0, float* o1, int M, int end, int amap) {
        MMJob j; j.A = A; j.W = W; j.C = C; j.q0 = q0; j.q1 = q1; j.o0 = o0; j.o1 = o1;
        j.M = M; j.blk_end = end; j.amap = amap; return j;
    };
    auto mkea = [](const int* off, const int* srcs, const float* es, const float* ed,
                   const float* Hsrc, const float* Xdst, float* Out, int nseg, int mode) {
        EASet s; s.off = off; s.srcs = srcs; s.es = es; s.ed = ed; s.Hsrc = Hsrc;
        s.Xdst = Xdst; s.Out = Out; s.nseg = nseg; s.mode = mode; return s;
    };
    EASet eaNone = mkea(nullptr, nullptr, nullptr, nullptr, nullptr, nullptr, nullptr, 0, 0);
    MMJob jNone = mkjob(nullptr, nullptr, nullptr, nullptr, nullptr, nullptr, nullptr, 0, BIG, 0);

    // ---- CSR build (3 segmentations, fused)
    hipMemsetAsync(cnt3, 0, (size_t)(2 * Nq + NEWSq) * 4, stream);
    k_count_all<<<(TOTE + 255) / 256, 256, 0, stream>>>(ei_dst, bi_node, bi_news, cg, cbn, cbw);
    k_scan3<<<3, 1024, 0, stream>>>(cg, cbn, cbw, g_off, bn_off, bw_off, curg, curbn, curbw);
    k_scatter_all<<<(TOTE + 255) / 256, 256, 0, stream>>>(ei_src, ei_dst, bi_news, bi_node,
            curg, curbn, curbw, g_src, bn_src, bw_src);

    // ---- titles: per-word score = tanh(word_emb@te_W + te_b)@te_v
    k_mm_tanh<<<nbWS, 256, 0, stream>>>(word_emb, te_W, WVOCq, te_b, te_v, wscore);
    k_title_pool<<<Bq * Sq, 128, 0, stream>>>(title_tok, wscore, word_emb,
            hist_seqs, hist_lens, pos_seq, pos_len, neg_seqs, neg_lens, UTraw, news1);
    // ---- node embeddings
    k_embed<<<(Nq * 32 + 255) / 256, 256, 0, stream>>>(nodes, ent_emb, v0, Nq);

    // ---- QKV1 (UTraw) + GAT1 matmul (v0) fused
    {
        MMJobs js;
        js.j[0] = mkjob(UTraw, ue1_Wq, qb, nullptr, nullptr, nullptr, nullptr, MH, nbMH, 0);
        js.j[1] = mkjob(UTraw, ue1_Wk, kb, nullptr, nullptr, nullptr, nullptr, MH, 2 * nbMH, 0);
        js.j[2] = mkjob(UTraw, ue1_Wv, vb, nullptr, nullptr, nullptr, nullptr, MH, 3 * nbMH, 0);
        js.j[3] = mkjob(v0, g1_W, nodeS2 /*note: kb==nodeS2 conflict? no: kb used now*/, nullptr, nullptr, nullptr, nullptr, 0, BIG, 0);
        // GAT1 matmul must not alias qb/kb/vb; run it in the NEXT launch instead (v1 path), keep 3 jobs here
        js.j[3] = jNone;
        k_mm_jobs<<<3 * nbMH, 256, 0, stream>>>(js);
    }
    k_self_attn<<<Bq, 256, 0, stream>>>(qb, kb, vb, news1, Sq * 128, nullptr);

    // ---- GAT 1 matmul (after attn1 frees nodeS1) + aggregate
    {
        MMJobs js;
        js.j[0] = mkjob(v0, g1_W, nodeS1, g1_as, g1_ad, es_node, ed_node, Nq, nbNode, 0);
        js.j[1] = js.j[2] = js.j[3] = jNone;
        k_mm_jobs<<<nbNode, 256, 0, stream>>>(js);
    }
    k_edge_agg_w<<<(Nq + 3) / 4, 256, 0, stream>>>(
        mkea(g_off, g_src, es_node, ed_node, nodeS1, nullptr, v1, Nq, 0), eaNone,
        nullptr, nullptr, nullptr);

    // ---- cross 1: all four matmuls fused, then both edge_aggs fused
    {
        MMJobs js;
        js.j[0] = mkjob(news1, cg1_Ws, newsS1, cg1_as, nullptr, es_news, nullptr, NEWSq, nbNews, 0);
        js.j[1] = mkjob(v1,    cg1_Wd, nullptr, cg1_ad, nullptr, ed_node, nullptr, Nq, nbNews + nbNode, 0);
        js.j[2] = mkjob(v1,    cg1_Ws, nodeS1,  cg1_as, nullptr, es_node, nullptr, Nq, nbNews + 2 * nbNode, 0);
        js.j[3] = mkjob(news1, cg1_Wd, nullptr, cg1_ad, nullptr, ed_news, nullptr, NEWSq, BIG, 0);
        k_mm_jobs<<<2 * nbNews + 2 * nbNode, 256, 0, stream>>>(js);
    }
    k_edge_agg_w<<<(Nq + NEWSq + 3) / 4, 256, 0, stream>>>(
        mkea(bn_off, bn_src, es_news, ed_node, newsS1, v1, nc1, Nq, 1),
        mkea(bw_off, bw_src, es_node, ed_news, nodeS1, news1, NC1, NEWSq, 1),
        nullptr, nullptr, nullptr);

    // ---- attn2 (NC1 user slots gathered directly; tail copy fused) 
    {
        MMJobs js;
        js.j[0] = mkjob(NC1, ue2_Wq, qb, nullptr, nullptr, nullptr, nullptr, MH, nbMH, 1);
        js.j[1] = mkjob(NC1, ue2_Wk, kb, nullptr, nullptr, nullptr, nullptr, MH, 2 * nbMH, 1);
        js.j[2] = mkjob(NC1, ue2_Wv, vb, nullptr, nullptr, nullptr, nullptr, MH, 3 * nbMH, 1);
        js.j[3] = jNone;
        k_mm_jobs<<<3 * nbMH, 256, 0, stream>>>(js);
    }
    k_self_attn<<<Bq, 256, 0, stream>>>(qb, kb, vb, news2, Sq * 128, NC1);

    // ---- GAT 2
    {
        MMJobs js;
        js.j[0] = mkjob(nc1, g2_W, nodeS1, g2_as, g2_ad, es_node, ed_node, Nq, nbNode, 0);
        js.j[1] = js.j[2] = js.j[3] = jNone;
        k_mm_jobs<<<nbNode, 256, 0, stream>>>(js);
    }
    k_edge_agg_w<<<(Nq + 3) / 4, 256, 0, stream>>>(
        mkea(g_off, g_src, es_node, ed_node, nodeS1, nullptr, v2, Nq, 0), eaNone,
        nullptr, nullptr, nullptr);

    // ---- cross 2 (+ fused gate dot on nc2 segment)
    {
        MMJobs js;
        js.j[0] = mkjob(news2, cg2_Ws, newsS1, cg2_as, nullptr, es_news, nullptr, NEWSq, nbNews, 0);
        js.j[1] = mkjob(v2,    cg2_Wd, nullptr, cg2_ad, nullptr, ed_node, nullptr, Nq, nbNews + nbNode, 0);
        js.j[2] = mkjob(v2,    cg2_Ws, nodeS1,  cg2_as, nullptr, es_node, nullptr, Nq, nbNews + 2 * nbNode, 0);
        js.j[3] = mkjob(news2, cg2_Wd, nullptr, cg2_ad, nullptr, ed_news, nullptr, NEWSq, BIG, 0);
        k_mm_jobs<<<2 * nbNews + 2 * nbNode, 256, 0, stream>>>(js);
    }
    k_edge_agg_w<<<(Nq + NEWSq + 3) / 4, 256, 0, stream>>>(
        mkea(bn_off, bn_src, es_news, ed_node, newsS1, v2, nc2, Nq, 1),
        mkea(bw_off, bw_src, es_node, ed_news, nodeS1, news2, NC2, NEWSq, 1),
        gate_W, gate_b, gate);

    // ---- mask pool on nc2 (gate from fused edge_agg) — independent of attn3 chain
    k_mask_pool<<<Bq * 6, 128, 0, stream>>>(nc2, gate, hist_mask, pos_mask, neg_masks, pooled);

    // ---- attn3 (NC2 user slots -> UT3)
    {
        MMJobs js;
        js.j[0] = mkjob(NC2, ue3_Wq, qb, nullptr, nullptr, nullptr, nullptr, MH, nbMH, 1);
        js.j[1] = mkjob(NC2, ue3_Wk, kb, nullptr, nullptr, nullptr, nullptr, MH, 2 * nbMH, 1);
        js.j[2] = mkjob(NC2, ue3_Wv, vb, nullptr, nullptr, nullptr, nullptr, MH, 3 * nbMH, 1);
        js.j[3] = jNone;
        k_mm_jobs<<<3 * nbMH, 256, 0, stream>>>(js);
    }
    k_self_attn<<<Bq, 256, 0, stream>>>(qb, kb, vb, UT3, Hq * 128, nullptr);

    // ---- user_vec = attend_pool(UT3, sa)
    k_mm_tanh<<<nbMH, 256, 0, stream>>>(UT3, sa_W, MH, sa_b, sa_v, score_bh);
    k_user_pool<<<Bq, 128, 0, stream>>>(UT3, score_bh, user_vec);

    // ---- final gated scores
    k_final<<<Bq * NEG1q, 128, 0, stream>>>(pooled, user_vec, NC2, ww_W, ww_b, out);
}

// Round 6
// 691.190 us; speedup vs baseline: 1.1118x; 1.1118x over previous
//
#include <hip/hip_runtime.h>
#include <math.h>

#define Bq    128
#define Dq    128
#define Hq    50
#define NEGq  4
#define Lq    30
#define Sq    55      // H + 1 + NEG
#define NPGq  80
#define Nq    10240   // B * NPG
#define Eq    163840  // N * 16
#define NEWSq 7040    // B * S
#define BEq   28160   // NEWS * 4
#define WVOCq 50000
#define NEG1q 5

__device__ __forceinline__ float leaky_f(float x) { return x > 0.f ? x : 0.2f * x; }

// ---------------------------------------------------------------- CSR build (fused x3)
__global__ void k_count_all(const int* __restrict__ ei_dst, const int* __restrict__ bi_node,
                            const int* __restrict__ bi_news,
                            int* __restrict__ cg, int* __restrict__ cbn, int* __restrict__ cbw) {
    int e = blockIdx.x * blockDim.x + threadIdx.x;
    if (e < Eq) atomicAdd(&cg[ei_dst[e]], 1);
    else if (e < Eq + BEq) atomicAdd(&cbn[bi_node[e - Eq]], 1);
    else if (e < Eq + 2 * BEq) atomicAdd(&cbw[bi_news[e - Eq - BEq]], 1);
}

__global__ __launch_bounds__(1024) void k_scan3(
        const int* __restrict__ cg, const int* __restrict__ cbn, const int* __restrict__ cbw,
        int* __restrict__ og, int* __restrict__ obn, int* __restrict__ obw,
        int* __restrict__ curg, int* __restrict__ curbn, int* __restrict__ curbw) {
    __shared__ int part[1024];
    const int* cnt; int* off; int* cur; int n;
    if (blockIdx.x == 0)      { cnt = cg;  off = og;  cur = curg;  n = Nq; }
    else if (blockIdx.x == 1) { cnt = cbn; off = obn; cur = curbn; n = Nq; }
    else                      { cnt = cbw; off = obw; cur = curbw; n = NEWSq; }
    int tid = threadIdx.x;
    int chunk = (n + 1023) >> 10;
    int s0 = tid * chunk;
    int s1 = s0 + chunk; if (s1 > n) s1 = n;
    int s = 0;
    for (int i = s0; i < s1; ++i) s += cnt[i];
    part[tid] = s;
    __syncthreads();
    for (int d = 1; d < 1024; d <<= 1) {
        int v = (tid >= d) ? part[tid - d] : 0;
        __syncthreads();
        part[tid] += v;
        __syncthreads();
    }
    int base = (tid > 0) ? part[tid - 1] : 0;
    for (int i = s0; i < s1; ++i) { off[i] = base; cur[i] = base; base += cnt[i]; }
    if (tid == 0) off[n] = part[1023];
}

__global__ void k_scatter_all(const int* __restrict__ ei_src, const int* __restrict__ ei_dst,
                              const int* __restrict__ bi_news, const int* __restrict__ bi_node,
                              int* __restrict__ curg, int* __restrict__ curbn, int* __restrict__ curbw,
                              int* __restrict__ g_out, int* __restrict__ bn_out, int* __restrict__ bw_out) {
    int e = blockIdx.x * blockDim.x + threadIdx.x;
    if (e < Eq) {
        int slot = atomicAdd(&curg[ei_dst[e]], 1);
        g_out[slot] = ei_src[e];
    } else if (e < Eq + BEq) {
        int i = e - Eq;
        int slot = atomicAdd(&curbn[bi_node[i]], 1);
        bn_out[slot] = bi_news[i];
    } else if (e < Eq + 2 * BEq) {
        int i = e - Eq - BEq;
        int slot = atomicAdd(&curbw[bi_news[i]], 1);
        bw_out[slot] = bi_node[i];
    }
}

// ---------------------------------------------------------------- gathers
__global__ void k_embed(const int* __restrict__ nodes, const float* __restrict__ ent,
                        float* __restrict__ out, int n) {
    int i = blockIdx.x * blockDim.x + threadIdx.x;
    if (i < n * 32) {
        int r = i >> 5, d = i & 31;
        ((float4*)out)[i] = ((const float4*)(ent + (long)nodes[r] * 128))[d];
    }
}

// ---------------------------------------------------------------- matmul core
// Tile: 32 rows x 128 cols, 256 threads, 4x4 micro-tile (R4-proven config).
// f32 FMA chains over full 32-deep K slices, f64 merge once per slice.
// LDS = 16KB(W) + 4KB(A) = 20KB -> 8 blocks/CU cap.
// amap=1: A row r maps to user slot (r/50)*55 + r%50 (NC gather).
#define MMROWS 32

#define MM4(RR, CC, WC) \
    f[RR][CC] = fmaf(a.x, w0.WC, f[RR][CC]); \
    f[RR][CC] = fmaf(a.y, w1.WC, f[RR][CC]); \
    f[RR][CC] = fmaf(a.z, w2.WC, f[RR][CC]); \
    f[RR][CC] = fmaf(a.w, w3.WC, f[RR][CC]);

__device__ __forceinline__ void mm_compute(float* sW, float (*sA)[32],
        const float* __restrict__ A, const float* __restrict__ W,
        int M, int r0, int amap, double acc[4][4]) {
    int tid = threadIdx.x;
    int tx = tid & 31;                    // col group -> j0 = tx*4
    int ty = tid >> 5;                    // row group -> rows ty*4 .. ty*4+3
    int j0 = tx * 4;
#pragma unroll
    for (int rr = 0; rr < 4; ++rr)
#pragma unroll
        for (int cc = 0; cc < 4; ++cc) acc[rr][cc] = 0.0;

    for (int ks = 0; ks < 4; ++ks) {
        __syncthreads();
        const float4* W4 = (const float4*)(W + ks * 32 * 128);
        float4* sW4 = (float4*)sW;
#pragma unroll
        for (int i = tid; i < 32 * 32; i += 256) sW4[i] = W4[i];
        {
            int r = tid >> 3, c4 = tid & 7;     // 32 rows x 8 float4
            int gr = r0 + r;
            float4 v = make_float4(0.f, 0.f, 0.f, 0.f);
            if (gr < M) {
                long pr = amap ? (long)((gr / Hq) * Sq + gr % Hq) : (long)gr;
                v = *(const float4*)(A + pr * 128 + ks * 32 + c4 * 4);
            }
            *(float4*)&sA[r][c4 * 4] = v;
        }
        __syncthreads();
        // 32-deep f32 FMA chain, single f64 merge per slice
        float f[4][4];
#pragma unroll
        for (int rr = 0; rr < 4; ++rr)
#pragma unroll
            for (int cc = 0; cc < 4; ++cc) f[rr][cc] = 0.f;
#pragma unroll
        for (int k = 0; k < 32; k += 4) {
            float4 w0 = *(const float4*)&sW[(k + 0) * 128 + j0];
            float4 w1 = *(const float4*)&sW[(k + 1) * 128 + j0];
            float4 w2 = *(const float4*)&sW[(k + 2) * 128 + j0];
            float4 w3 = *(const float4*)&sW[(k + 3) * 128 + j0];
#pragma unroll
            for (int rr = 0; rr < 4; ++rr) {
                float4 a = *(const float4*)&sA[ty * 4 + rr][k];
                MM4(rr, 0, x) MM4(rr, 1, y) MM4(rr, 2, z) MM4(rr, 3, w)
            }
        }
#pragma unroll
        for (int rr = 0; rr < 4; ++rr)
#pragma unroll
            for (int cc = 0; cc < 4; ++cc) acc[rr][cc] += (double)f[rr][cc];
    }
}

// ---- generic job-table matmul: C store (opt) + row dots (opt, 1 or 2)
struct MMJob {
    const float* A; const float* W; float* C;
    const float* q0; const float* q1;
    float* o0; float* o1;
    int M; int blk_end; int amap;
};
struct MMJobs { MMJob j[4]; };

__global__ __launch_bounds__(256) void k_mm_jobs(MMJobs js) {
    __shared__ float sW[32 * 128];
    __shared__ float sA[MMROWS][32];
    int bid = blockIdx.x;
    int ji = 0, blk0 = 0;
#pragma unroll
    for (int t = 0; t < 3; ++t)
        if (bid >= js.j[t].blk_end) { ji = t + 1; blk0 = js.j[t].blk_end; }
    MMJob J = js.j[ji];
    double acc[4][4];
    int r0 = (bid - blk0) * MMROWS;
    mm_compute(sW, sA, J.A, J.W, J.M, r0, J.amap, acc);
    int tid = threadIdx.x, tx = tid & 31, ty = tid >> 5;
    int j0 = tx * 4;
    if (J.C) {
#pragma unroll
        for (int rr = 0; rr < 4; ++rr) {
            int r = r0 + ty * 4 + rr;
            if (r < J.M) {
                float4 o = make_float4((float)acc[rr][0], (float)acc[rr][1],
                                       (float)acc[rr][2], (float)acc[rr][3]);
                *(float4*)&J.C[(long)r * 128 + j0] = o;
            }
        }
    }
    if (J.o0) {
        float q0c[4], q1c[4];
        bool two = (J.q1 != nullptr);
#pragma unroll
        for (int cc = 0; cc < 4; ++cc) {
            q0c[cc] = J.q0[j0 + cc];
            q1c[cc] = two ? J.q1[j0 + cc] : 0.f;
        }
#pragma unroll
        for (int rr = 0; rr < 4; ++rr) {
            int r = r0 + ty * 4 + rr;
            double d0 = 0.0, d1 = 0.0;
#pragma unroll
            for (int cc = 0; cc < 4; ++cc) {
                double c = (double)(float)acc[rr][cc];   // f32-rounded C
                d0 += c * (double)q0c[cc];
                d1 += c * (double)q1c[cc];
            }
            for (int o = 16; o > 0; o >>= 1) {
                d0 += __shfl_xor(d0, o);
                if (two) d1 += __shfl_xor(d1, o);
            }
            if ((tid & 31) == 0 && r < J.M) {
                J.o0[r] = (float)d0;
                if (two) J.o1[r] = (float)d1;
            }
        }
    }
}

// ---- tanh-dot matmul: o0[r] = sum_j tanh(C[r][j]+q0[j])*q1[j]  (no C store)
__global__ __launch_bounds__(256) void k_mm_tanh(const float* __restrict__ A,
        const float* __restrict__ W, int M,
        const float* __restrict__ q0, const float* __restrict__ q1,
        float* __restrict__ o0) {
    __shared__ float sW[32 * 128];
    __shared__ float sA[MMROWS][32];
    double acc[4][4];
    int r0 = blockIdx.x * MMROWS;
    mm_compute(sW, sA, A, W, M, r0, 0, acc);
    int tid = threadIdx.x, tx = tid & 31, ty = tid >> 5;
    int j0 = tx * 4;
    float q0c[4], q1c[4];
#pragma unroll
    for (int cc = 0; cc < 4; ++cc) { q0c[cc] = q0[j0 + cc]; q1c[cc] = q1[j0 + cc]; }
#pragma unroll
    for (int rr = 0; rr < 4; ++rr) {
        int r = r0 + ty * 4 + rr;
        double s = 0.0;
#pragma unroll
        for (int cc = 0; cc < 4; ++cc) {
            float t = (float)acc[rr][cc] + q0c[cc];
            s += (double)tanhf(t) * (double)q1c[cc];
        }
        for (int o = 16; o > 0; o >>= 1) s += __shfl_xor(s, o);
        if ((tid & 31) == 0 && r < M) o0[r] = (float)s;
    }
}

// ---------------------------------------------------------------- title pooling
__global__ __launch_bounds__(128) void k_title_pool(
        const int* __restrict__ title_tok, const float* __restrict__ wscore,
        const float* __restrict__ wemb,
        const int* __restrict__ hist_seqs, const int* __restrict__ hist_lens,
        const int* __restrict__ pos_seq, const int* __restrict__ pos_len,
        const int* __restrict__ neg_seqs, const int* __restrict__ neg_lens,
        float* __restrict__ UTraw, float* __restrict__ news1) {
    int t = blockIdx.x;
    int b = t / Sq, s = t % Sq;
    int nid, len; float* dst;
    if (s < Hq)       { nid = hist_seqs[b * Hq + s]; len = hist_lens[b * Hq + s]; dst = UTraw + (long)(b * Hq + s) * 128; }
    else if (s == Hq) { nid = pos_seq[b];            len = pos_len[b];            dst = news1 + (long)t * 128; }
    else { int g = s - Hq - 1; nid = neg_seqs[b * NEGq + g]; len = neg_lens[b * NEGq + g]; dst = news1 + (long)t * 128; }

    __shared__ int tok[Lq];
    __shared__ float wgt[Lq];
    __shared__ double sden;
    int tid = threadIdx.x;
    if (tid < Lq) tok[tid] = title_tok[(long)nid * Lq + tid];
    __syncthreads();
    if (tid < 64) {   // first wave does the softmax over len<=30 lanes
        float sc = (tid < len) ? wscore[tok[tid]] : -1e30f;
        float mx = sc;
        for (int o = 32; o > 0; o >>= 1) mx = fmaxf(mx, __shfl_xor(mx, o));
        float e = (tid < len) ? (float)exp((double)(sc - mx)) : 0.f;
        if (tid < Lq) wgt[tid] = e;
        double ds = (double)e;
        for (int o = 32; o > 0; o >>= 1) ds += __shfl_xor(ds, o);
        if (tid == 0) sden = ds;
    }
    __syncthreads();
    double den = sden;
    double acc = 0.0;
    for (int l = 0; l < len; ++l)
        acc += (double)wgt[l] * (double)wemb[(long)tok[l] * 128 + tid];
    dst[tid] = (float)(acc / den);
}

// ---------------------------------------------------------------- edge aggregation: wave per segment
#define WMAXK 128
struct EASet {
    const int* off; const int* srcs;
    const float* es; const float* ed;
    const float* Hsrc; const float* Xdst;
    float* Out; int nseg; int mode;
};

__global__ __launch_bounds__(256) void k_edge_agg_w(EASet a, EASet b,
        const float* __restrict__ gW, const float* __restrict__ gb, float* __restrict__ gout) {
    __shared__ int   sSrc[4][WMAXK];
    __shared__ float sE[4][WMAXK];
    int wv = threadIdx.x >> 6, lane = threadIdx.x & 63;
    int g = blockIdx.x * 4 + wv;
    if (g >= a.nseg + b.nseg) return;
    bool isA = g < a.nseg;
    EASet S = isA ? a : b;
    int n = isA ? g : g - a.nseg;
    int s0 = S.off[n], k = S.off[n + 1] - s0;
    int d0 = lane * 2;
    float o0, o1;
    if (k == 0) {
        if (S.mode) { float2 x = *(const float2*)&S.Xdst[(long)n * 128 + d0]; o0 = x.x; o1 = x.y; }
        else { o0 = 0.f; o1 = 0.f; }   // elu(0)=0
    } else {
        float edn = S.ed[n];
        float mloc = -1e30f;
        for (int j = lane; j < k; j += 64) {
            int sidx = S.srcs[s0 + j];
            float e = leaky_f(S.es[sidx] + edn);
            if (j < WMAXK) { sSrc[wv][j] = sidx; sE[wv][j] = e; }
            mloc = fmaxf(mloc, e);
        }
        for (int o = 32; o > 0; o >>= 1) mloc = fmaxf(mloc, __shfl_xor(mloc, o));
        float m = mloc;
        double dloc = 0.0;
        for (int j = lane; j < k; j += 64) {
            float e = (j < WMAXK) ? sE[wv][j] : leaky_f(S.es[S.srcs[s0 + j]] + edn);
            float ex = (float)exp((double)(e - m));
            if (j < WMAXK) sE[wv][j] = ex;
            dloc += (double)ex;
        }
        for (int o = 32; o > 0; o >>= 1) dloc += __shfl_xor(dloc, o);
        double den = dloc + 1e-16;
        for (int j = lane; j < k && j < WMAXK; j += 64)
            sE[wv][j] = (float)((double)sE[wv][j] / den);     // alpha
        double a0 = 0.0, a1 = 0.0;
        for (int j = 0; j < k; ++j) {
            float alpha; int sidx;
            if (j < WMAXK) { alpha = sE[wv][j]; sidx = sSrc[wv][j]; }
            else {
                sidx = S.srcs[s0 + j];
                float e = leaky_f(S.es[sidx] + edn);
                float ex = (float)exp((double)(e - m));
                alpha = (float)((double)ex / den);
            }
            float2 h = *(const float2*)&S.Hsrc[(long)sidx * 128 + d0];
            a0 += (double)alpha * (double)h.x;
            a1 += (double)alpha * (double)h.y;
        }
        float v0f = (float)a0, v1f = (float)a1;
        o0 = (v0f > 0.f) ? v0f : (float)expm1((double)v0f);
        o1 = (v1f > 0.f) ? v1f : (float)expm1((double)v1f);
        if (S.mode) {
            float2 x = *(const float2*)&S.Xdst[(long)n * 128 + d0];
            o0 += x.x; o1 += x.y;
        }
    }
    *(float2*)&S.Out[(long)n * 128 + d0] = make_float2(o0, o1);
    if (isA && gout) {   // fused gate = f32(dot(out_row, gW)) + gb
        double part = (double)o0 * (double)gW[d0] + (double)o1 * (double)gW[d0 + 1];
        for (int o = 32; o > 0; o >>= 1) part += __shfl_xor(part, o);
        if (lane == 0) gout[n] = (float)part + gb[0];
    }
}

// ---------------------------------------------------------------- self-attention (flat-parallel, one block per batch)
__global__ __launch_bounds__(256) void k_self_attn(const float* __restrict__ Q, const float* __restrict__ K,
                                                   const float* __restrict__ V, float* __restrict__ Out,
                                                   int ob_stride, const float* __restrict__ tail_src) {
    __shared__ float sQ[Hq][129];
    __shared__ float sK[Hq][129];
    __shared__ float sV[Hq * 128];
    __shared__ float sEx[Hq][52];
    __shared__ double sInv[Hq];
    const double SQRTD = (double)11.3137085f;  // f32(sqrt(128))
    int b = blockIdx.x;
    int tid = threadIdx.x;
    const float* Qb = Q + (long)b * Hq * 128;
    const float* Kb = K + (long)b * Hq * 128;
    const float* Vb = V + (long)b * Hq * 128;
    for (int idx = tid; idx < Hq * 128; idx += 256) {
        int r = idx >> 7, i = idx & 127;
        sQ[r][i] = Qb[idx];
        sK[r][i] = Kb[idx];
        sV[idx] = Vb[idx];
    }
    __syncthreads();
    // scores: each thread ~10 of the 2500 (r,j) dots (16-chunk f32, f64 merge)
    for (int p = tid; p < Hq * Hq; p += 256) {
        int r = p / Hq, j = p - r * Hq;
        double acc = 0.0;
#pragma unroll
        for (int c0 = 0; c0 < 128; c0 += 16) {
            float f = 0.f;
#pragma unroll
            for (int i = 0; i < 16; ++i) f = fmaf(sQ[r][c0 + i], sK[j][c0 + i], f);
            acc += (double)f;
        }
        sEx[r][j] = (float)(acc / SQRTD);
    }
    __syncthreads();
    // softmax: wave per row, shuffle reductions
    int wv = tid >> 6, lane = tid & 63;
    for (int r = wv; r < Hq; r += 4) {
        float s = (lane < Hq) ? sEx[r][lane] : -1e30f;
        float mx = s;
        for (int o = 32; o > 0; o >>= 1) mx = fmaxf(mx, __shfl_xor(mx, o));
        float ex = (lane < Hq) ? (float)exp((double)(s - mx)) : 0.f;
        double ds = (double)ex;
        for (int o = 32; o > 0; o >>= 1) ds += __shfl_xor(ds, o);
        if (lane < Hq) sEx[r][lane] = ex;
        if (lane == 0) sInv[r] = 1.0 / ds;
    }
    __syncthreads();
    // PV: each thread 25 (r,d) outputs
    int d = tid & 127, rh = tid >> 7;
    for (int r = rh; r < Hq; r += 2) {
        double acc = 0.0;
        for (int c0 = 0; c0 < Hq; c0 += 16) {
            float f = 0.f;
            int ce = (c0 + 16 < Hq) ? c0 + 16 : Hq;
            for (int c = c0; c < ce; ++c) f = fmaf(sEx[r][c], sV[c * 128 + d], f);
            acc += (double)f;
        }
        Out[(long)b * ob_stride + (long)r * 128 + d] = (float)(acc * sInv[r]);
    }
    // fold target-row copy (news2 <- NC1 tail)
    if (tail_src) {
        for (int idx = tid; idx < NEG1q * 128; idx += 256) {
            int rr = Hq + (idx >> 7), dd = idx & 127;
            Out[(long)b * ob_stride + (long)rr * 128 + dd] = tail_src[((long)(b * Sq + rr)) * 128 + dd];
        }
    }
}

// ---------------------------------------------------------------- masked pooling
__global__ __launch_bounds__(128) void k_mask_pool(const float* __restrict__ X, const float* __restrict__ gate,
        const int* __restrict__ hist_mask, const int* __restrict__ pos_mask, const int* __restrict__ neg_masks,
        float* __restrict__ pooled) {
    int blk = blockIdx.x;
    int b = blk / 6, s = blk % 6;
    int tid = threadIdx.x;
    __shared__ float sEx[NPGq];
    __shared__ float redf[128];
    __shared__ double redd[128];
    int base = b * NPGq;
    float logit = -1e30f; int mk = 0;
    if (tid < NPGq) {
        int n = base + tid;
        mk = (s == 0) ? hist_mask[n] : (s == 1) ? pos_mask[n] : neg_masks[n * NEGq + (s - 2)];
        logit = (mk > 0) ? gate[n] : -1000000000.0f;
    }
    redf[tid] = logit; __syncthreads();
    for (int d = 64; d > 0; d >>= 1) { if (tid < d) redf[tid] = fmaxf(redf[tid], redf[tid + d]); __syncthreads(); }
    float mx = redf[0];
    float ex = 0.f;
    if (tid < NPGq && mk > 0) ex = (float)exp((double)(logit - mx));
    if (tid < NPGq) sEx[tid] = ex;
    redd[tid] = (double)ex; __syncthreads();
    for (int d = 64; d > 0; d >>= 1) { if (tid < d) redd[tid] += redd[tid + d]; __syncthreads(); }
    double den = redd[0] + 1e-16;
    double acc = 0.0;
    for (int c0 = 0; c0 < NPGq; c0 += 16) {
        float f = 0.f;
#pragma unroll
        for (int c = 0; c < 16; ++c)
            f = fmaf(sEx[c0 + c], X[((long)(base + c0 + c)) * 128 + tid], f);
        acc += (double)f;
    }
    pooled[(long)blk * 128 + tid] = (float)(acc / den);
}

// ---------------------------------------------------------------- user final pool (softmax over H)
__global__ __launch_bounds__(128) void k_user_pool(const float* __restrict__ UT3, const float* __restrict__ score,
                                                   float* __restrict__ uvec) {
    int b = blockIdx.x, tid = threadIdx.x;
    __shared__ float sEx[Hq];
    __shared__ float redf[128];
    __shared__ double redd[128];
    float sv = (tid < Hq) ? score[b * Hq + tid] : -1e30f;
    redf[tid] = sv; __syncthreads();
    for (int d = 64; d > 0; d >>= 1) { if (tid < d) redf[tid] = fmaxf(redf[tid], redf[tid + d]); __syncthreads(); }
    float mx = redf[0];
    float ex = (tid < Hq) ? (float)exp((double)(sv - mx)) : 0.f;
    if (tid < Hq) sEx[tid] = ex;
    redd[tid] = (double)ex; __syncthreads();
    for (int d = 64; d > 0; d >>= 1) { if (tid < d) redd[tid] += redd[tid + d]; __syncthreads(); }
    double den = redd[0];
    double acc = 0.0;
    for (int h = 0; h < Hq; ++h)
        acc += (double)sEx[h] * (double)UT3[((long)(b * Hq + h)) * 128 + tid];
    uvec[(long)b * 128 + tid] = (float)(acc / den);
}

// ---------------------------------------------------------------- final gated score
__global__ __launch_bounds__(128) void k_final(const float* __restrict__ pooled, const float* __restrict__ uvec,
        const float* __restrict__ NC2, const float* __restrict__ wwW, const float* __restrict__ wwb,
        float* __restrict__ out) {
    int blk = blockIdx.x;
    int b = blk / NEG1q, g = blk % NEG1q;
    int tid = threadIdx.x;
    __shared__ double redd[128];
    const float* ug = pooled + (long)(b * 6 + 0) * 128;
    const float* tg = pooled + (long)(b * 6 + 1 + g) * 128;
    const float* ut = uvec + (long)b * 128;
    const float* tt = NC2 + (long)(b * Sq + Hq + g) * 128;
    double w0 = (double)wwW[tid], w1 = (double)wwW[128 + tid];

    redd[tid] = (double)ug[tid] * w0 + (double)ut[tid] * w1;
    __syncthreads();
    for (int d = 64; d > 0; d >>= 1) { if (tid < d) redd[tid] += redd[tid + d]; __syncthreads(); }
    float su = (float)redd[0] + wwb[0];
    float uwf = (float)(1.0 / (1.0 + exp(-(double)su)));
    __syncthreads();

    redd[tid] = (double)tg[tid] * w0 + (double)tt[tid] * w1;
    __syncthreads();
    for (int d = 64; d > 0; d >>= 1) { if (tid < d) redd[tid] += redd[tid + d]; __syncthreads(); }
    float st = (float)redd[0] + wwb[0];
    float twf = (float)(1.0 / (1.0 + exp(-(double)st)));
    __syncthreads();

    float uh = uwf * ug[tid] + (1.f - uwf) * ut[tid];
    float th = twf * tg[tid] + (1.f - twf) * tt[tid];
    redd[tid] = (double)uh * (double)th;
    __syncthreads();
    for (int d = 64; d > 0; d >>= 1) { if (tid < d) redd[tid] += redd[tid + d]; __syncthreads(); }
    if (tid == 0) out[blk] = (float)redd[0];
}

// ================================================================ launch
extern "C" void kernel_launch(void* const* d_in, const int* in_sizes, int n_in,
                              void* d_out, int out_size, void* d_ws, size_t ws_size,
                              hipStream_t stream) {
    // ---- inputs
    const int*   nodes      = (const int*)d_in[0];
    const int*   ei_src     = (const int*)d_in[1];
    const int*   ei_dst     = ei_src + Eq;
    const int*   bi_news    = (const int*)d_in[2];   // bi_edge_index[0]: news ids
    const int*   bi_node    = bi_news + BEq;         // bi_edge_index[1]: node ids
    const int*   hist_mask  = (const int*)d_in[4];
    const int*   pos_mask   = (const int*)d_in[5];
    const int*   neg_masks  = (const int*)d_in[6];
    const int*   hist_seqs  = (const int*)d_in[7];
    const int*   hist_lens  = (const int*)d_in[8];
    const int*   pos_seq    = (const int*)d_in[9];
    const int*   pos_len    = (const int*)d_in[10];
    const int*   neg_seqs   = (const int*)d_in[11];
    const int*   neg_lens   = (const int*)d_in[12];
    const int*   title_tok  = (const int*)d_in[13];
    const float* ent_emb    = (const float*)d_in[14];
    const float* word_emb   = (const float*)d_in[15];
    const float* te_W  = (const float*)d_in[16];
    const float* te_b  = (const float*)d_in[17];
    const float* te_v  = (const float*)d_in[18];
    const float* ue1_Wq = (const float*)d_in[19];
    const float* ue1_Wk = (const float*)d_in[20];
    const float* ue1_Wv = (const float*)d_in[21];
    const float* ue2_Wq = (const float*)d_in[22];
    const float* ue2_Wk = (const float*)d_in[23];
    const float* ue2_Wv = (const float*)d_in[24];
    const float* ue3_Wq = (const float*)d_in[25];
    const float* ue3_Wk = (const float*)d_in[26];
    const float* ue3_Wv = (const float*)d_in[27];
    const float* g1_W  = (const float*)d_in[28];
    const float* g1_as = (const float*)d_in[29];
    const float* g1_ad = (const float*)d_in[30];
    const float* g2_W  = (const float*)d_in[31];
    const float* g2_as = (const float*)d_in[32];
    const float* g2_ad = (const float*)d_in[33];
    const float* cg1_Ws = (const float*)d_in[34];
    const float* cg1_Wd = (const float*)d_in[35];
    const float* cg1_as = (const float*)d_in[36];
    const float* cg1_ad = (const float*)d_in[37];
    const float* cg2_Ws = (const float*)d_in[38];
    const float* cg2_Wd = (const float*)d_in[39];
    const float* cg2_as = (const float*)d_in[40];
    const float* cg2_ad = (const float*)d_in[41];
    const float* sa_W  = (const float*)d_in[42];
    const float* sa_b  = (const float*)d_in[43];
    const float* sa_v  = (const float*)d_in[44];
    const float* gate_W = (const float*)d_in[45];
    const float* gate_b = (const float*)d_in[46];
    const float* ww_W  = (const float*)d_in[47];
    const float* ww_b  = (const float*)d_in[48];
    float* out = (float*)d_out;

    // ---- workspace carve
    char* p = (char*)d_ws;
    auto alloc = [&](size_t bytes) -> void* {
        void* r = (void*)p;
        p += (bytes + 255) & ~(size_t)255;
        return r;
    };
    int* g_off  = (int*)alloc((Nq + 1) * 4);
    int* bn_off = (int*)alloc((Nq + 1) * 4);
    int* bw_off = (int*)alloc((NEWSq + 1) * 4);
    int* g_src  = (int*)alloc(Eq * 4);
    int* bn_src = (int*)alloc(BEq * 4);
    int* bw_src = (int*)alloc(BEq * 4);
    int* cnt3   = (int*)alloc((2 * Nq + NEWSq) * 4);   // cg | cbn | cbw contiguous
    int* cur3   = (int*)alloc((2 * Nq + NEWSq) * 4);
    int* cg  = cnt3, *cbn = cnt3 + Nq, *cbw = cnt3 + 2 * Nq;
    int* curg = cur3, *curbn = cur3 + Nq, *curbw = cur3 + 2 * Nq;

    float* wscore  = (float*)alloc(WVOCq * 4);
    float* UTraw   = (float*)alloc((size_t)Bq * Hq * 128 * 4);
    float* UT3     = (float*)alloc((size_t)Bq * Hq * 128 * 4);
    float* news1   = (float*)alloc((size_t)NEWSq * 128 * 4);
    float* NC1     = (float*)alloc((size_t)NEWSq * 128 * 4);
    float* news2   = (float*)alloc((size_t)NEWSq * 128 * 4);
    float* NC2     = (float*)alloc((size_t)NEWSq * 128 * 4);
    float* newsS1  = (float*)alloc((size_t)NEWSq * 128 * 4);   // vb / hs_news
    float* v0      = (float*)alloc((size_t)Nq * 128 * 4);
    float* v1      = (float*)alloc((size_t)Nq * 128 * 4);
    float* nc1     = (float*)alloc((size_t)Nq * 128 * 4);
    float* v2      = (float*)alloc((size_t)Nq * 128 * 4);
    float* nc2     = (float*)alloc((size_t)Nq * 128 * 4);
    float* nodeS1  = (float*)alloc((size_t)Nq * 128 * 4);      // qb / hs_node
    float* nodeS2  = (float*)alloc((size_t)Nq * 128 * 4);      // kb
    float* es_node = (float*)alloc(Nq * 4);
    float* ed_node = (float*)alloc(Nq * 4);
    float* es_news = (float*)alloc(NEWSq * 4);
    float* ed_news = (float*)alloc(NEWSq * 4);
    float* gate    = (float*)alloc(Nq * 4);
    float* score_bh = (float*)alloc(Bq * Hq * 4);
    float* user_vec = (float*)alloc(Bq * 128 * 4);
    float* pooled   = (float*)alloc((size_t)Bq * 6 * 128 * 4);

    float* qb = nodeS1;   // aliases (temporally disjoint)
    float* kb = nodeS2;
    float* vb = newsS1;

    const int MH = Bq * Hq;          // 6400
    const int nbMH   = (MH + MMROWS - 1) / MMROWS;      // 200
    const int nbNode = (Nq + MMROWS - 1) / MMROWS;      // 320
    const int nbNews = (NEWSq + MMROWS - 1) / MMROWS;   // 220
    const int nbWS   = (WVOCq + MMROWS - 1) / MMROWS;   // 1563
    const int TOTE = Eq + 2 * BEq;
    const int BIG = 0x7fffffff;

    auto mkjob = [](const float* A, const float* W, float* C, const float* q0, const float* q1,
                    float* o0, float* o1, int M, int end, int amap) {
        MMJob j; j.A = A; j.W = W; j.C = C; j.q0 = q0; j.q1 = q1; j.o0 = o0; j.o1 = o1;
        j.M = M; j.blk_end = end; j.amap = amap; return j;
    };
    auto mkea = [](const int* off, const int* srcs, const float* es, const float* ed,
                   const float* Hsrc, const float* Xdst, float* Out, int nseg, int mode) {
        EASet s; s.off = off; s.srcs = srcs; s.es = es; s.ed = ed; s.Hsrc = Hsrc;
        s.Xdst = Xdst; s.Out = Out; s.nseg = nseg; s.mode = mode; return s;
    };
    EASet eaNone = mkea(nullptr, nullptr, nullptr, nullptr, nullptr, nullptr, nullptr, 0, 0);
    MMJob jNone = mkjob(nullptr, nullptr, nullptr, nullptr, nullptr, nullptr, nullptr, 0, BIG, 0);

    // ---- CSR build (3 segmentations, fused)
    hipMemsetAsync(cnt3, 0, (size_t)(2 * Nq + NEWSq) * 4, stream);
    k_count_all<<<(TOTE + 255) / 256, 256, 0, stream>>>(ei_dst, bi_node, bi_news, cg, cbn, cbw);
    k_scan3<<<3, 1024, 0, stream>>>(cg, cbn, cbw, g_off, bn_off, bw_off, curg, curbn, curbw);
    k_scatter_all<<<(TOTE + 255) / 256, 256, 0, stream>>>(ei_src, ei_dst, bi_news, bi_node,
            curg, curbn, curbw, g_src, bn_src, bw_src);

    // ---- titles: per-word score = tanh(word_emb@te_W + te_b)@te_v
    k_mm_tanh<<<nbWS, 256, 0, stream>>>(word_emb, te_W, WVOCq, te_b, te_v, wscore);
    k_title_pool<<<Bq * Sq, 128, 0, stream>>>(title_tok, wscore, word_emb,
            hist_seqs, hist_lens, pos_seq, pos_len, neg_seqs, neg_lens, UTraw, news1);
    // ---- node embeddings
    k_embed<<<(Nq * 32 + 255) / 256, 256, 0, stream>>>(nodes, ent_emb, v0, Nq);

    // ---- QKV1 (UTraw)
    {
        MMJobs js;
        js.j[0] = mkjob(UTraw, ue1_Wq, qb, nullptr, nullptr, nullptr, nullptr, MH, nbMH, 0);
        js.j[1] = mkjob(UTraw, ue1_Wk, kb, nullptr, nullptr, nullptr, nullptr, MH, 2 * nbMH, 0);
        js.j[2] = mkjob(UTraw, ue1_Wv, vb, nullptr, nullptr, nullptr, nullptr, MH, 3 * nbMH, 0);
        js.j[3] = jNone;
        k_mm_jobs<<<3 * nbMH, 256, 0, stream>>>(js);
    }
    k_self_attn<<<Bq, 256, 0, stream>>>(qb, kb, vb, news1, Sq * 128, nullptr);

    // ---- GAT 1 matmul (after attn1 frees nodeS1) + aggregate
    {
        MMJobs js;
        js.j[0] = mkjob(v0, g1_W, nodeS1, g1_as, g1_ad, es_node, ed_node, Nq, nbNode, 0);
        js.j[1] = js.j[2] = js.j[3] = jNone;
        k_mm_jobs<<<nbNode, 256, 0, stream>>>(js);
    }
    k_edge_agg_w<<<(Nq + 3) / 4, 256, 0, stream>>>(
        mkea(g_off, g_src, es_node, ed_node, nodeS1, nullptr, v1, Nq, 0), eaNone,
        nullptr, nullptr, nullptr);

    // ---- cross 1: all four matmuls fused, then both edge_aggs fused
    {
        MMJobs js;
        js.j[0] = mkjob(news1, cg1_Ws, newsS1, cg1_as, nullptr, es_news, nullptr, NEWSq, nbNews, 0);
        js.j[1] = mkjob(v1,    cg1_Wd, nullptr, cg1_ad, nullptr, ed_node, nullptr, Nq, nbNews + nbNode, 0);
        js.j[2] = mkjob(v1,    cg1_Ws, nodeS1,  cg1_as, nullptr, es_node, nullptr, Nq, nbNews + 2 * nbNode, 0);
        js.j[3] = mkjob(news1, cg1_Wd, nullptr, cg1_ad, nullptr, ed_news, nullptr, NEWSq, BIG, 0);
        k_mm_jobs<<<2 * nbNews + 2 * nbNode, 256, 0, stream>>>(js);
    }
    k_edge_agg_w<<<(Nq + NEWSq + 3) / 4, 256, 0, stream>>>(
        mkea(bn_off, bn_src, es_news, ed_node, newsS1, v1, nc1, Nq, 1),
        mkea(bw_off, bw_src, es_node, ed_news, nodeS1, news1, NC1, NEWSq, 1),
        nullptr, nullptr, nullptr);

    // ---- attn2 (NC1 user slots gathered directly; tail copy fused)
    {
        MMJobs js;
        js.j[0] = mkjob(NC1, ue2_Wq, qb, nullptr, nullptr, nullptr, nullptr, MH, nbMH, 1);
        js.j[1] = mkjob(NC1, ue2_Wk, kb, nullptr, nullptr, nullptr, nullptr, MH, 2 * nbMH, 1);
        js.j[2] = mkjob(NC1, ue2_Wv, vb, nullptr, nullptr, nullptr, nullptr, MH, 3 * nbMH, 1);
        js.j[3] = jNone;
        k_mm_jobs<<<3 * nbMH, 256, 0, stream>>>(js);
    }
    k_self_attn<<<Bq, 256, 0, stream>>>(qb, kb, vb, news2, Sq * 128, NC1);

    // ---- GAT 2
    {
        MMJobs js;
        js.j[0] = mkjob(nc1, g2_W, nodeS1, g2_as, g2_ad, es_node, ed_node, Nq, nbNode, 0);
        js.j[1] = js.j[2] = js.j[3] = jNone;
        k_mm_jobs<<<nbNode, 256, 0, stream>>>(js);
    }
    k_edge_agg_w<<<(Nq + 3) / 4, 256, 0, stream>>>(
        mkea(g_off, g_src, es_node, ed_node, nodeS1, nullptr, v2, Nq, 0), eaNone,
        nullptr, nullptr, nullptr);

    // ---- cross 2 (+ fused gate dot on nc2 segment)
    {
        MMJobs js;
        js.j[0] = mkjob(news2, cg2_Ws, newsS1, cg2_as, nullptr, es_news, nullptr, NEWSq, nbNews, 0);
        js.j[1] = mkjob(v2,    cg2_Wd, nullptr, cg2_ad, nullptr, ed_node, nullptr, Nq, nbNews + nbNode, 0);
        js.j[2] = mkjob(v2,    cg2_Ws, nodeS1,  cg2_as, nullptr, es_node, nullptr, Nq, nbNews + 2 * nbNode, 0);
        js.j[3] = mkjob(news2, cg2_Wd, nullptr, cg2_ad, nullptr, ed_news, nullptr, NEWSq, BIG, 0);
        k_mm_jobs<<<2 * nbNews + 2 * nbNode, 256, 0, stream>>>(js);
    }
    k_edge_agg_w<<<(Nq + NEWSq + 3) / 4, 256, 0, stream>>>(
        mkea(bn_off, bn_src, es_news, ed_node, newsS1, v2, nc2, Nq, 1),
        mkea(bw_off, bw_src, es_node, ed_news, nodeS1, news2, NC2, NEWSq, 1),
        gate_W, gate_b, gate);

    // ---- mask pool on nc2 (gate from fused edge_agg) — independent of attn3 chain
    k_mask_pool<<<Bq * 6, 128, 0, stream>>>(nc2, gate, hist_mask, pos_mask, neg_masks, pooled);

    // ---- attn3 (NC2 user slots -> UT3)
    {
        MMJobs js;
        js.j[0] = mkjob(NC2, ue3_Wq, qb, nullptr, nullptr, nullptr, nullptr, MH, nbMH, 1);
        js.j[1] = mkjob(NC2, ue3_Wk, kb, nullptr, nullptr, nullptr, nullptr, MH, 2 * nbMH, 1);
        js.j[2] = mkjob(NC2, ue3_Wv, vb, nullptr, nullptr, nullptr, nullptr, MH, 3 * nbMH, 1);
        js.j[3] = jNone;
        k_mm_jobs<<<3 * nbMH, 256, 0, stream>>>(js);
    }
    k_self_attn<<<Bq, 256, 0, stream>>>(qb, kb, vb, UT3, Hq * 128, nullptr);

    // ---- user_vec = attend_pool(UT3, sa)
    k_mm_tanh<<<nbMH, 256, 0, stream>>>(UT3, sa_W, MH, sa_b, sa_v, score_bh);
    k_user_pool<<<Bq, 128, 0, stream>>>(UT3, score_bh, user_vec);

    // ---- final gated scores
    k_final<<<Bq * NEG1q, 128, 0, stream>>>(pooled, user_vec, NC2, ww_W, ww_b, out);
}

// Round 7
// 660.262 us; speedup vs baseline: 1.1638x; 1.0468x over previous
//
#include <hip/hip_runtime.h>
#include <math.h>

#define Bq    128
#define Dq    128
#define Hq    50
#define NEGq  4
#define Lq    30
#define Sq    55      // H + 1 + NEG
#define NPGq  80
#define Nq    10240   // B * NPG
#define Eq    163840  // N * 16
#define NEWSq 7040    // B * S
#define BEq   28160   // NEWS * 4
#define WVOCq 50000
#define NEG1q 5

__device__ __forceinline__ float leaky_f(float x) { return x > 0.f ? x : 0.2f * x; }

// ---------------------------------------------------------------- matmul core (R6-proven)
// Tile: 32 rows x 128 cols, 256 threads, 4x4 micro-tile.
// f32 FMA chains over full 32-deep K slices, f64 merge once per slice.
// LDS = 16KB(W) + 4KB(A) = 20KB. amap=1: row r -> (r/50)*55 + r%50 (NC gather).
#define MMROWS 32

#define MM4(RR, CC, WC) \
    f[RR][CC] = fmaf(a.x, w0.WC, f[RR][CC]); \
    f[RR][CC] = fmaf(a.y, w1.WC, f[RR][CC]); \
    f[RR][CC] = fmaf(a.z, w2.WC, f[RR][CC]); \
    f[RR][CC] = fmaf(a.w, w3.WC, f[RR][CC]);

__device__ __forceinline__ void mm_compute(float* sW, float (*sA)[32],
        const float* __restrict__ A, const float* __restrict__ W,
        int M, int r0, int amap, double acc[4][4]) {
    int tid = threadIdx.x;
    int tx = tid & 31;
    int ty = tid >> 5;
    int j0 = tx * 4;
#pragma unroll
    for (int rr = 0; rr < 4; ++rr)
#pragma unroll
        for (int cc = 0; cc < 4; ++cc) acc[rr][cc] = 0.0;

    for (int ks = 0; ks < 4; ++ks) {
        __syncthreads();
        const float4* W4 = (const float4*)(W + ks * 32 * 128);
        float4* sW4 = (float4*)sW;
#pragma unroll
        for (int i = tid; i < 32 * 32; i += 256) sW4[i] = W4[i];
        {
            int r = tid >> 3, c4 = tid & 7;
            int gr = r0 + r;
            float4 v = make_float4(0.f, 0.f, 0.f, 0.f);
            if (gr < M) {
                long pr = amap ? (long)((gr / Hq) * Sq + gr % Hq) : (long)gr;
                v = *(const float4*)(A + pr * 128 + ks * 32 + c4 * 4);
            }
            *(float4*)&sA[r][c4 * 4] = v;
        }
        __syncthreads();
        float f[4][4];
#pragma unroll
        for (int rr = 0; rr < 4; ++rr)
#pragma unroll
            for (int cc = 0; cc < 4; ++cc) f[rr][cc] = 0.f;
#pragma unroll
        for (int k = 0; k < 32; k += 4) {
            float4 w0 = *(const float4*)&sW[(k + 0) * 128 + j0];
            float4 w1 = *(const float4*)&sW[(k + 1) * 128 + j0];
            float4 w2 = *(const float4*)&sW[(k + 2) * 128 + j0];
            float4 w3 = *(const float4*)&sW[(k + 3) * 128 + j0];
#pragma unroll
            for (int rr = 0; rr < 4; ++rr) {
                float4 a = *(const float4*)&sA[ty * 4 + rr][k];
                MM4(rr, 0, x) MM4(rr, 1, y) MM4(rr, 2, z) MM4(rr, 3, w)
            }
        }
#pragma unroll
        for (int rr = 0; rr < 4; ++rr)
#pragma unroll
            for (int cc = 0; cc < 4; ++cc) acc[rr][cc] += (double)f[rr][cc];
    }
}

// tanh-dot epilogue body (word-score / sa): o0[r] = sum_j tanh(C+q0)*q1
__device__ __forceinline__ void mm_tanh_body(float* sW, float (*sA)[32],
        const float* __restrict__ A, const float* __restrict__ W, int M, int r0,
        const float* __restrict__ q0, const float* __restrict__ q1, float* __restrict__ o0) {
    double acc[4][4];
    mm_compute(sW, sA, A, W, M, r0, 0, acc);
    int tid = threadIdx.x, tx = tid & 31, ty = tid >> 5;
    int j0 = tx * 4;
    float q0c[4], q1c[4];
#pragma unroll
    for (int cc = 0; cc < 4; ++cc) { q0c[cc] = q0[j0 + cc]; q1c[cc] = q1[j0 + cc]; }
#pragma unroll
    for (int rr = 0; rr < 4; ++rr) {
        int r = r0 + ty * 4 + rr;
        double s = 0.0;
#pragma unroll
        for (int cc = 0; cc < 4; ++cc) {
            float t = (float)acc[rr][cc] + q0c[cc];
            s += (double)tanhf(t) * (double)q1c[cc];
        }
        for (int o = 16; o > 0; o >>= 1) s += __shfl_xor(s, o);
        if ((tid & 31) == 0 && r < M) o0[r] = (float)s;
    }
}

__global__ __launch_bounds__(256) void k_mm_tanh(const float* __restrict__ A,
        const float* __restrict__ W, int M,
        const float* __restrict__ q0, const float* __restrict__ q1, float* __restrict__ o0) {
    __shared__ float sW[32 * 128];
    __shared__ float sA[MMROWS][32];
    mm_tanh_body(sW, sA, A, W, M, blockIdx.x * MMROWS, q0, q1, o0);
}

// ---- generic job-table matmul
struct MMJob {
    const float* A; const float* W; float* C;
    const float* q0; const float* q1;
    float* o0; float* o1;
    int M; int blk_end; int amap;
};
struct MMJobs { MMJob j[4]; };

__global__ __launch_bounds__(256) void k_mm_jobs(MMJobs js) {
    __shared__ float sW[32 * 128];
    __shared__ float sA[MMROWS][32];
    int bid = blockIdx.x;
    int ji = 0, blk0 = 0;
#pragma unroll
    for (int t = 0; t < 3; ++t)
        if (bid >= js.j[t].blk_end) { ji = t + 1; blk0 = js.j[t].blk_end; }
    MMJob J = js.j[ji];
    double acc[4][4];
    int r0 = (bid - blk0) * MMROWS;
    mm_compute(sW, sA, J.A, J.W, J.M, r0, J.amap, acc);
    int tid = threadIdx.x, tx = tid & 31, ty = tid >> 5;
    int j0 = tx * 4;
    if (J.C) {
#pragma unroll
        for (int rr = 0; rr < 4; ++rr) {
            int r = r0 + ty * 4 + rr;
            if (r < J.M) {
                float4 o = make_float4((float)acc[rr][0], (float)acc[rr][1],
                                       (float)acc[rr][2], (float)acc[rr][3]);
                *(float4*)&J.C[(long)r * 128 + j0] = o;
            }
        }
    }
    if (J.o0) {
        float q0c[4], q1c[4];
        bool two = (J.q1 != nullptr);
#pragma unroll
        for (int cc = 0; cc < 4; ++cc) {
            q0c[cc] = J.q0[j0 + cc];
            q1c[cc] = two ? J.q1[j0 + cc] : 0.f;
        }
#pragma unroll
        for (int rr = 0; rr < 4; ++rr) {
            int r = r0 + ty * 4 + rr;
            double d0 = 0.0, d1 = 0.0;
#pragma unroll
            for (int cc = 0; cc < 4; ++cc) {
                double c = (double)(float)acc[rr][cc];
                d0 += c * (double)q0c[cc];
                d1 += c * (double)q1c[cc];
            }
            for (int o = 16; o > 0; o >>= 1) {
                d0 += __shfl_xor(d0, o);
                if (two) d1 += __shfl_xor(d1, o);
            }
            if ((tid & 31) == 0 && r < J.M) {
                J.o0[r] = (float)d0;
                if (two) J.o1[r] = (float)d1;
            }
        }
    }
}

// ---------------------------------------------------------------- misc1: CSR count || embed || word-score
__global__ __launch_bounds__(256) void k_misc1(
        const int* __restrict__ ei_dst, const int* __restrict__ bi_node, const int* __restrict__ bi_news,
        int* __restrict__ cg, int* __restrict__ cbn, int* __restrict__ cbw,
        const int* __restrict__ nodes, const float* __restrict__ ent, float* __restrict__ v0,
        const float* __restrict__ wemb, const float* __restrict__ teW,
        const float* __restrict__ teb, const float* __restrict__ tev, float* __restrict__ wscore,
        int n_count, int n_embed) {
    __shared__ float sW[32 * 128];
    __shared__ float sA[MMROWS][32];
    int blk = blockIdx.x;
    if (blk < n_count) {
        int e = blk * 256 + threadIdx.x;
        if (e < Eq) atomicAdd(&cg[ei_dst[e]], 1);
        else if (e < Eq + BEq) atomicAdd(&cbn[bi_node[e - Eq]], 1);
        else if (e < Eq + 2 * BEq) atomicAdd(&cbw[bi_news[e - Eq - BEq]], 1);
    } else if (blk < n_count + n_embed) {
        int i = (blk - n_count) * 256 + threadIdx.x;
        if (i < Nq * 32) {
            int r = i >> 5, d = i & 31;
            ((float4*)v0)[i] = ((const float4*)(ent + (long)nodes[r] * 128))[d];
        }
    } else {
        int r0 = (blk - n_count - n_embed) * MMROWS;
        mm_tanh_body(sW, sA, wemb, teW, WVOCq, r0, teb, tev, wscore);
    }
}

// ---------------------------------------------------------------- scan (3 blocks)
__global__ __launch_bounds__(1024) void k_scan3(
        const int* __restrict__ cg, const int* __restrict__ cbn, const int* __restrict__ cbw,
        int* __restrict__ og, int* __restrict__ obn, int* __restrict__ obw,
        int* __restrict__ curg, int* __restrict__ curbn, int* __restrict__ curbw) {
    __shared__ int part[1024];
    const int* cnt; int* off; int* cur; int n;
    if (blockIdx.x == 0)      { cnt = cg;  off = og;  cur = curg;  n = Nq; }
    else if (blockIdx.x == 1) { cnt = cbn; off = obn; cur = curbn; n = Nq; }
    else                      { cnt = cbw; off = obw; cur = curbw; n = NEWSq; }
    int tid = threadIdx.x;
    int chunk = (n + 1023) >> 10;
    int s0 = tid * chunk;
    int s1 = s0 + chunk; if (s1 > n) s1 = n;
    int s = 0;
    for (int i = s0; i < s1; ++i) s += cnt[i];
    part[tid] = s;
    __syncthreads();
    for (int d = 1; d < 1024; d <<= 1) {
        int v = (tid >= d) ? part[tid - d] : 0;
        __syncthreads();
        part[tid] += v;
        __syncthreads();
    }
    int base = (tid > 0) ? part[tid - 1] : 0;
    for (int i = s0; i < s1; ++i) { off[i] = base; cur[i] = base; base += cnt[i]; }
    if (tid == 0) off[n] = part[1023];
}

// ---------------------------------------------------------------- misc2: CSR scatter || title-pool (2/block)
__global__ __launch_bounds__(256) void k_misc2(
        const int* __restrict__ ei_src, const int* __restrict__ ei_dst,
        const int* __restrict__ bi_news, const int* __restrict__ bi_node,
        int* __restrict__ curg, int* __restrict__ curbn, int* __restrict__ curbw,
        int* __restrict__ g_out, int* __restrict__ bn_out, int* __restrict__ bw_out,
        const int* __restrict__ title_tok, const float* __restrict__ wscore,
        const float* __restrict__ wemb,
        const int* __restrict__ hist_seqs, const int* __restrict__ hist_lens,
        const int* __restrict__ pos_seq, const int* __restrict__ pos_len,
        const int* __restrict__ neg_seqs, const int* __restrict__ neg_lens,
        float* __restrict__ UTraw, float* __restrict__ news1, int n_scatter) {
    __shared__ int tok[2][Lq];
    __shared__ float wgt[2][Lq];
    __shared__ double sden[2];
    int blk = blockIdx.x;
    if (blk < n_scatter) {
        int e = blk * 256 + threadIdx.x;
        if (e < Eq) {
            int slot = atomicAdd(&curg[ei_dst[e]], 1);
            g_out[slot] = ei_src[e];
        } else if (e < Eq + BEq) {
            int i = e - Eq;
            int slot = atomicAdd(&curbn[bi_node[i]], 1);
            bn_out[slot] = bi_news[i];
        } else if (e < Eq + 2 * BEq) {
            int i = e - Eq - BEq;
            int slot = atomicAdd(&curbw[bi_news[i]], 1);
            bw_out[slot] = bi_node[i];
        }
        return;
    }
    int half = threadIdx.x >> 7;
    int tid = threadIdx.x & 127;
    int t = (blk - n_scatter) * 2 + half;   // title index < Bq*Sq (7040, even)
    int b = t / Sq, s = t % Sq;
    int nid, len; float* dst;
    if (s < Hq)       { nid = hist_seqs[b * Hq + s]; len = hist_lens[b * Hq + s]; dst = UTraw + (long)(b * Hq + s) * 128; }
    else if (s == Hq) { nid = pos_seq[b];            len = pos_len[b];            dst = news1 + (long)t * 128; }
    else { int g = s - Hq - 1; nid = neg_seqs[b * NEGq + g]; len = neg_lens[b * NEGq + g]; dst = news1 + (long)t * 128; }

    if (tid < Lq) tok[half][tid] = title_tok[(long)nid * Lq + tid];
    __syncthreads();
    if (tid < 64) {   // one wave per half does the softmax
        float sc = (tid < len) ? wscore[tok[half][tid]] : -1e30f;
        float mx = sc;
        for (int o = 32; o > 0; o >>= 1) mx = fmaxf(mx, __shfl_xor(mx, o));
        float e = (tid < len) ? (float)exp((double)(sc - mx)) : 0.f;
        if (tid < Lq) wgt[half][tid] = e;
        double ds = (double)e;
        for (int o = 32; o > 0; o >>= 1) ds += __shfl_xor(ds, o);
        if (tid == 0) sden[half] = ds;
    }
    __syncthreads();
    double den = sden[half];
    double acc = 0.0;
    for (int l = 0; l < len; ++l)
        acc += (double)wgt[half][l] * (double)wemb[(long)tok[half][l] * 128 + tid];
    dst[tid] = (float)(acc / den);
}

// ---------------------------------------------------------------- edge aggregation: wave per segment
#define WMAXK 128
struct EASet {
    const int* off; const int* srcs;
    const float* es; const float* ed;
    const float* Hsrc; const float* Xdst;
    float* Out; int nseg; int mode;
};

__global__ __launch_bounds__(256) void k_edge_agg_w(EASet a, EASet b,
        const float* __restrict__ gW, const float* __restrict__ gb, float* __restrict__ gout) {
    __shared__ int   sSrc[4][WMAXK];
    __shared__ float sE[4][WMAXK];
    int wv = threadIdx.x >> 6, lane = threadIdx.x & 63;
    int g = blockIdx.x * 4 + wv;
    if (g >= a.nseg + b.nseg) return;
    bool isA = g < a.nseg;
    EASet S = isA ? a : b;
    int n = isA ? g : g - a.nseg;
    int s0 = S.off[n], k = S.off[n + 1] - s0;
    int d0 = lane * 2;
    float o0, o1;
    if (k == 0) {
        if (S.mode) { float2 x = *(const float2*)&S.Xdst[(long)n * 128 + d0]; o0 = x.x; o1 = x.y; }
        else { o0 = 0.f; o1 = 0.f; }
    } else {
        float edn = S.ed[n];
        float mloc = -1e30f;
        for (int j = lane; j < k; j += 64) {
            int sidx = S.srcs[s0 + j];
            float e = leaky_f(S.es[sidx] + edn);
            if (j < WMAXK) { sSrc[wv][j] = sidx; sE[wv][j] = e; }
            mloc = fmaxf(mloc, e);
        }
        for (int o = 32; o > 0; o >>= 1) mloc = fmaxf(mloc, __shfl_xor(mloc, o));
        float m = mloc;
        double dloc = 0.0;
        for (int j = lane; j < k; j += 64) {
            float e = (j < WMAXK) ? sE[wv][j] : leaky_f(S.es[S.srcs[s0 + j]] + edn);
            float ex = (float)exp((double)(e - m));
            if (j < WMAXK) sE[wv][j] = ex;
            dloc += (double)ex;
        }
        for (int o = 32; o > 0; o >>= 1) dloc += __shfl_xor(dloc, o);
        double den = dloc + 1e-16;
        for (int j = lane; j < k && j < WMAXK; j += 64)
            sE[wv][j] = (float)((double)sE[wv][j] / den);
        double a0 = 0.0, a1 = 0.0;
        for (int j = 0; j < k; ++j) {
            float alpha; int sidx;
            if (j < WMAXK) { alpha = sE[wv][j]; sidx = sSrc[wv][j]; }
            else {
                sidx = S.srcs[s0 + j];
                float e = leaky_f(S.es[sidx] + edn);
                float ex = (float)exp((double)(e - m));
                alpha = (float)((double)ex / den);
            }
            float2 h = *(const float2*)&S.Hsrc[(long)sidx * 128 + d0];
            a0 += (double)alpha * (double)h.x;
            a1 += (double)alpha * (double)h.y;
        }
        float v0f = (float)a0, v1f = (float)a1;
        o0 = (v0f > 0.f) ? v0f : (float)expm1((double)v0f);
        o1 = (v1f > 0.f) ? v1f : (float)expm1((double)v1f);
        if (S.mode) {
            float2 x = *(const float2*)&S.Xdst[(long)n * 128 + d0];
            o0 += x.x; o1 += x.y;
        }
    }
    *(float2*)&S.Out[(long)n * 128 + d0] = make_float2(o0, o1);
    if (isA && gout) {
        double part = (double)o0 * (double)gW[d0] + (double)o1 * (double)gW[d0 + 1];
        for (int o = 32; o > 0; o >>= 1) part += __shfl_xor(part, o);
        if (lane == 0) gout[n] = (float)part + gb[0];
    }
}

// ---------------------------------------------------------------- self-attention (flat-parallel)
__global__ __launch_bounds__(256) void k_self_attn(const float* __restrict__ Q, const float* __restrict__ K,
                                                   const float* __restrict__ V, float* __restrict__ Out,
                                                   int ob_stride, const float* __restrict__ tail_src) {
    __shared__ float sQ[Hq][129];
    __shared__ float sK[Hq][129];
    __shared__ float sV[Hq * 128];
    __shared__ float sEx[Hq][52];
    __shared__ double sInv[Hq];
    const double SQRTD = (double)11.3137085f;
    int b = blockIdx.x;
    int tid = threadIdx.x;
    const float* Qb = Q + (long)b * Hq * 128;
    const float* Kb = K + (long)b * Hq * 128;
    const float* Vb = V + (long)b * Hq * 128;
    for (int idx = tid; idx < Hq * 128; idx += 256) {
        int r = idx >> 7, i = idx & 127;
        sQ[r][i] = Qb[idx];
        sK[r][i] = Kb[idx];
        sV[idx] = Vb[idx];
    }
    __syncthreads();
    for (int p = tid; p < Hq * Hq; p += 256) {
        int r = p / Hq, j = p - r * Hq;
        double acc = 0.0;
#pragma unroll
        for (int c0 = 0; c0 < 128; c0 += 16) {
            float f = 0.f;
#pragma unroll
            for (int i = 0; i < 16; ++i) f = fmaf(sQ[r][c0 + i], sK[j][c0 + i], f);
            acc += (double)f;
        }
        sEx[r][j] = (float)(acc / SQRTD);
    }
    __syncthreads();
    int wv = tid >> 6, lane = tid & 63;
    for (int r = wv; r < Hq; r += 4) {
        float s = (lane < Hq) ? sEx[r][lane] : -1e30f;
        float mx = s;
        for (int o = 32; o > 0; o >>= 1) mx = fmaxf(mx, __shfl_xor(mx, o));
        float ex = (lane < Hq) ? (float)exp((double)(s - mx)) : 0.f;
        double ds = (double)ex;
        for (int o = 32; o > 0; o >>= 1) ds += __shfl_xor(ds, o);
        if (lane < Hq) sEx[r][lane] = ex;
        if (lane == 0) sInv[r] = 1.0 / ds;
    }
    __syncthreads();
    int d = tid & 127, rh = tid >> 7;
    for (int r = rh; r < Hq; r += 2) {
        double acc = 0.0;
        for (int c0 = 0; c0 < Hq; c0 += 16) {
            float f = 0.f;
            int ce = (c0 + 16 < Hq) ? c0 + 16 : Hq;
            for (int c = c0; c < ce; ++c) f = fmaf(sEx[r][c], sV[c * 128 + d], f);
            acc += (double)f;
        }
        Out[(long)b * ob_stride + (long)r * 128 + d] = (float)(acc * sInv[r]);
    }
    if (tail_src) {
        for (int idx = tid; idx < NEG1q * 128; idx += 256) {
            int rr = Hq + (idx >> 7), dd = idx & 127;
            Out[(long)b * ob_stride + (long)rr * 128 + dd] = tail_src[((long)(b * Sq + rr)) * 128 + dd];
        }
    }
}

// ---------------------------------------------------------------- fused final: user_pool + 2x mask_pool + gating
__global__ __launch_bounds__(128) void k_final_fused(
        const float* __restrict__ UT3, const float* __restrict__ score,
        const float* __restrict__ nc2, const float* __restrict__ gate,
        const int* __restrict__ hist_mask, const int* __restrict__ pos_mask, const int* __restrict__ neg_masks,
        const float* __restrict__ NC2, const float* __restrict__ wwW, const float* __restrict__ wwb,
        float* __restrict__ out) {
    int blk = blockIdx.x;
    int b = blk / NEG1q, g = blk % NEG1q;
    int tid = threadIdx.x;
    __shared__ float sEx[NPGq];
    __shared__ float sExU[Hq];
    __shared__ float redf[128];
    __shared__ double redd[128];

    // ---- user_pool recompute (identical op order to k_user_pool)
    float sv = (tid < Hq) ? score[b * Hq + tid] : -1e30f;
    redf[tid] = sv; __syncthreads();
    for (int d = 64; d > 0; d >>= 1) { if (tid < d) redf[tid] = fmaxf(redf[tid], redf[tid + d]); __syncthreads(); }
    float mxu = redf[0];
    float exu = (tid < Hq) ? (float)exp((double)(sv - mxu)) : 0.f;
    if (tid < Hq) sExU[tid] = exu;
    redd[tid] = (double)exu; __syncthreads();
    for (int d = 64; d > 0; d >>= 1) { if (tid < d) redd[tid] += redd[tid + d]; __syncthreads(); }
    double denu = redd[0];
    double accu = 0.0;
    for (int h = 0; h < Hq; ++h)
        accu += (double)sExU[h] * (double)UT3[((long)(b * Hq + h)) * 128 + tid];
    float ut = (float)(accu / denu);

    // ---- mask_pool recompute for a segment s (identical op order to k_mask_pool)
    int base = b * NPGq;
    float seg_out[2];
    int segs[2] = {0, 1 + g};
#pragma unroll
    for (int si = 0; si < 2; ++si) {
        int s = segs[si];
        __syncthreads();
        float logit = -1e30f; int mk = 0;
        if (tid < NPGq) {
            int n = base + tid;
            mk = (s == 0) ? hist_mask[n] : (s == 1) ? pos_mask[n] : neg_masks[n * NEGq + (s - 2)];
            logit = (mk > 0) ? gate[n] : -1000000000.0f;
        }
        redf[tid] = logit; __syncthreads();
        for (int d = 64; d > 0; d >>= 1) { if (tid < d) redf[tid] = fmaxf(redf[tid], redf[tid + d]); __syncthreads(); }
        float mx = redf[0];
        float ex = 0.f;
        if (tid < NPGq && mk > 0) ex = (float)exp((double)(logit - mx));
        if (tid < NPGq) sEx[tid] = ex;
        redd[tid] = (double)ex; __syncthreads();
        for (int d = 64; d > 0; d >>= 1) { if (tid < d) redd[tid] += redd[tid + d]; __syncthreads(); }
        double den = redd[0] + 1e-16;
        double acc = 0.0;
        for (int c0 = 0; c0 < NPGq; c0 += 16) {
            float f = 0.f;
#pragma unroll
            for (int c = 0; c < 16; ++c)
                f = fmaf(sEx[c0 + c], nc2[((long)(base + c0 + c)) * 128 + tid], f);
            acc += (double)f;
        }
        seg_out[si] = (float)(acc / den);
    }
    float ug = seg_out[0], tg = seg_out[1];
    float tt = NC2[(long)(b * Sq + Hq + g) * 128 + tid];
    double w0 = (double)wwW[tid], w1 = (double)wwW[128 + tid];

    __syncthreads();
    redd[tid] = (double)ug * w0 + (double)ut * w1;
    __syncthreads();
    for (int d = 64; d > 0; d >>= 1) { if (tid < d) redd[tid] += redd[tid + d]; __syncthreads(); }
    float su = (float)redd[0] + wwb[0];
    float uwf = (float)(1.0 / (1.0 + exp(-(double)su)));
    __syncthreads();

    redd[tid] = (double)tg * w0 + (double)tt * w1;
    __syncthreads();
    for (int d = 64; d > 0; d >>= 1) { if (tid < d) redd[tid] += redd[tid + d]; __syncthreads(); }
    float st = (float)redd[0] + wwb[0];
    float twf = (float)(1.0 / (1.0 + exp(-(double)st)));
    __syncthreads();

    float uh = uwf * ug + (1.f - uwf) * ut;
    float th = twf * tg + (1.f - twf) * tt;
    redd[tid] = (double)uh * (double)th;
    __syncthreads();
    for (int d = 64; d > 0; d >>= 1) { if (tid < d) redd[tid] += redd[tid + d]; __syncthreads(); }
    if (tid == 0) out[blk] = (float)redd[0];
}

// ================================================================ launch
extern "C" void kernel_launch(void* const* d_in, const int* in_sizes, int n_in,
                              void* d_out, int out_size, void* d_ws, size_t ws_size,
                              hipStream_t stream) {
    const int*   nodes      = (const int*)d_in[0];
    const int*   ei_src     = (const int*)d_in[1];
    const int*   ei_dst     = ei_src + Eq;
    const int*   bi_news    = (const int*)d_in[2];
    const int*   bi_node    = bi_news + BEq;
    const int*   hist_mask  = (const int*)d_in[4];
    const int*   pos_mask   = (const int*)d_in[5];
    const int*   neg_masks  = (const int*)d_in[6];
    const int*   hist_seqs  = (const int*)d_in[7];
    const int*   hist_lens  = (const int*)d_in[8];
    const int*   pos_seq    = (const int*)d_in[9];
    const int*   pos_len    = (const int*)d_in[10];
    const int*   neg_seqs   = (const int*)d_in[11];
    const int*   neg_lens   = (const int*)d_in[12];
    const int*   title_tok  = (const int*)d_in[13];
    const float* ent_emb    = (const float*)d_in[14];
    const float* word_emb   = (const float*)d_in[15];
    const float* te_W  = (const float*)d_in[16];
    const float* te_b  = (const float*)d_in[17];
    const float* te_v  = (const float*)d_in[18];
    const float* ue1_Wq = (const float*)d_in[19];
    const float* ue1_Wk = (const float*)d_in[20];
    const float* ue1_Wv = (const float*)d_in[21];
    const float* ue2_Wq = (const float*)d_in[22];
    const float* ue2_Wk = (const float*)d_in[23];
    const float* ue2_Wv = (const float*)d_in[24];
    const float* ue3_Wq = (const float*)d_in[25];
    const float* ue3_Wk = (const float*)d_in[26];
    const float* ue3_Wv = (const float*)d_in[27];
    const float* g1_W  = (const float*)d_in[28];
    const float* g1_as = (const float*)d_in[29];
    const float* g1_ad = (const float*)d_in[30];
    const float* g2_W  = (const float*)d_in[31];
    const float* g2_as = (const float*)d_in[32];
    const float* g2_ad = (const float*)d_in[33];
    const float* cg1_Ws = (const float*)d_in[34];
    const float* cg1_Wd = (const float*)d_in[35];
    const float* cg1_as = (const float*)d_in[36];
    const float* cg1_ad = (const float*)d_in[37];
    const float* cg2_Ws = (const float*)d_in[38];
    const float* cg2_Wd = (const float*)d_in[39];
    const float* cg2_as = (const float*)d_in[40];
    const float* cg2_ad = (const float*)d_in[41];
    const float* sa_W  = (const float*)d_in[42];
    const float* sa_b  = (const float*)d_in[43];
    const float* sa_v  = (const float*)d_in[44];
    const float* gate_W = (const float*)d_in[45];
    const float* gate_b = (const float*)d_in[46];
    const float* ww_W  = (const float*)d_in[47];
    const float* ww_b  = (const float*)d_in[48];
    float* out = (float*)d_out;

    char* p = (char*)d_ws;
    auto alloc = [&](size_t bytes) -> void* {
        void* r = (void*)p;
        p += (bytes + 255) & ~(size_t)255;
        return r;
    };
    int* g_off  = (int*)alloc((Nq + 1) * 4);
    int* bn_off = (int*)alloc((Nq + 1) * 4);
    int* bw_off = (int*)alloc((NEWSq + 1) * 4);
    int* g_src  = (int*)alloc(Eq * 4);
    int* bn_src = (int*)alloc(BEq * 4);
    int* bw_src = (int*)alloc(BEq * 4);
    int* cnt3   = (int*)alloc((2 * Nq + NEWSq) * 4);
    int* cur3   = (int*)alloc((2 * Nq + NEWSq) * 4);
    int* cg  = cnt3, *cbn = cnt3 + Nq, *cbw = cnt3 + 2 * Nq;
    int* curg = cur3, *curbn = cur3 + Nq, *curbw = cur3 + 2 * Nq;

    float* wscore  = (float*)alloc(WVOCq * 4);
    float* UTraw   = (float*)alloc((size_t)Bq * Hq * 128 * 4);
    float* UT3     = (float*)alloc((size_t)Bq * Hq * 128 * 4);
    float* news1   = (float*)alloc((size_t)NEWSq * 128 * 4);
    float* NC1     = (float*)alloc((size_t)NEWSq * 128 * 4);
    float* news2   = (float*)alloc((size_t)NEWSq * 128 * 4);
    float* NC2     = (float*)alloc((size_t)NEWSq * 128 * 4);
    float* newsS1  = (float*)alloc((size_t)NEWSq * 128 * 4);   // hs_news
    float* v0      = (float*)alloc((size_t)Nq * 128 * 4);
    float* v1      = (float*)alloc((size_t)Nq * 128 * 4);
    float* nc1     = (float*)alloc((size_t)Nq * 128 * 4);
    float* v2      = (float*)alloc((size_t)Nq * 128 * 4);
    float* nc2     = (float*)alloc((size_t)Nq * 128 * 4);
    float* nodeS1  = (float*)alloc((size_t)Nq * 128 * 4);      // hs_node / GAT h
    float* qb      = (float*)alloc((size_t)Bq * Hq * 128 * 4); // de-aliased QKV
    float* kb      = (float*)alloc((size_t)Bq * Hq * 128 * 4);
    float* vb      = (float*)alloc((size_t)Bq * Hq * 128 * 4);
    float* es_node = (float*)alloc(Nq * 4);
    float* ed_node = (float*)alloc(Nq * 4);
    float* es_news = (float*)alloc(NEWSq * 4);
    float* ed_news = (float*)alloc(NEWSq * 4);
    float* gate    = (float*)alloc(Nq * 4);
    float* score_bh = (float*)alloc(Bq * Hq * 4);

    const int MH = Bq * Hq;          // 6400
    const int nbMH   = (MH + MMROWS - 1) / MMROWS;      // 200
    const int nbNode = (Nq + MMROWS - 1) / MMROWS;      // 320
    const int nbNews = (NEWSq + MMROWS - 1) / MMROWS;   // 220
    const int TOTE = Eq + 2 * BEq;                      // 220160
    const int BIG = 0x7fffffff;
    const int nCount = (TOTE + 255) / 256;              // 860
    const int nEmbed = (Nq * 32 + 255) / 256;           // 1280
    const int nWS    = (WVOCq + MMROWS - 1) / MMROWS;   // 1563

    auto mkjob = [](const float* A, const float* W, float* C, const float* q0, const float* q1,
                    float* o0, float* o1, int M, int end, int amap) {
        MMJob j; j.A = A; j.W = W; j.C = C; j.q0 = q0; j.q1 = q1; j.o0 = o0; j.o1 = o1;
        j.M = M; j.blk_end = end; j.amap = amap; return j;
    };
    auto mkea = [](const int* off, const int* srcs, const float* es, const float* ed,
                   const float* Hsrc, const float* Xdst, float* Out, int nseg, int mode) {
        EASet s; s.off = off; s.srcs = srcs; s.es = es; s.ed = ed; s.Hsrc = Hsrc;
        s.Xdst = Xdst; s.Out = Out; s.nseg = nseg; s.mode = mode; return s;
    };
    EASet eaNone = mkea(nullptr, nullptr, nullptr, nullptr, nullptr, nullptr, nullptr, 0, 0);
    MMJob jNone = mkjob(nullptr, nullptr, nullptr, nullptr, nullptr, nullptr, nullptr, 0, BIG, 0);

    // L0: zero CSR counters
    hipMemsetAsync(cnt3, 0, (size_t)(2 * Nq + NEWSq) * 4, stream);
    // L1: count || embed || word-score
    k_misc1<<<nCount + nEmbed + nWS, 256, 0, stream>>>(
        ei_dst, bi_node, bi_news, cg, cbn, cbw,
        nodes, ent_emb, v0,
        word_emb, te_W, te_b, te_v, wscore, nCount, nEmbed);
    // L2: scan
    k_scan3<<<3, 1024, 0, stream>>>(cg, cbn, cbw, g_off, bn_off, bw_off, curg, curbn, curbw);
    // L3: scatter || title_pool
    k_misc2<<<nCount + (Bq * Sq) / 2, 256, 0, stream>>>(
        ei_src, ei_dst, bi_news, bi_node, curg, curbn, curbw, g_src, bn_src, bw_src,
        title_tok, wscore, word_emb,
        hist_seqs, hist_lens, pos_seq, pos_len, neg_seqs, neg_lens, UTraw, news1, nCount);

    // L4: QKV1 || GAT1 matmul (inputs UTraw + v0 both ready)
    {
        MMJobs js;
        js.j[0] = mkjob(UTraw, ue1_Wq, qb, nullptr, nullptr, nullptr, nullptr, MH, nbMH, 0);
        js.j[1] = mkjob(UTraw, ue1_Wk, kb, nullptr, nullptr, nullptr, nullptr, MH, 2 * nbMH, 0);
        js.j[2] = mkjob(UTraw, ue1_Wv, vb, nullptr, nullptr, nullptr, nullptr, MH, 3 * nbMH, 0);
        js.j[3] = mkjob(v0, g1_W, nodeS1, g1_as, g1_ad, es_node, ed_node, Nq, BIG, 0);
        k_mm_jobs<<<3 * nbMH + nbNode, 256, 0, stream>>>(js);
    }
    // L5: attn1
    k_self_attn<<<Bq, 256, 0, stream>>>(qb, kb, vb, news1, Sq * 128, nullptr);
    // L6: edge_agg GAT1
    k_edge_agg_w<<<(Nq + 3) / 4, 256, 0, stream>>>(
        mkea(g_off, g_src, es_node, ed_node, nodeS1, nullptr, v1, Nq, 0), eaNone,
        nullptr, nullptr, nullptr);

    // L7: cross1 matmuls (4 jobs)
    {
        MMJobs js;
        js.j[0] = mkjob(news1, cg1_Ws, newsS1, cg1_as, nullptr, es_news, nullptr, NEWSq, nbNews, 0);
        js.j[1] = mkjob(v1,    cg1_Wd, nullptr, cg1_ad, nullptr, ed_node, nullptr, Nq, nbNews + nbNode, 0);
        js.j[2] = mkjob(v1,    cg1_Ws, nodeS1,  cg1_as, nullptr, es_node, nullptr, Nq, nbNews + 2 * nbNode, 0);
        js.j[3] = mkjob(news1, cg1_Wd, nullptr, cg1_ad, nullptr, ed_news, nullptr, NEWSq, BIG, 0);
        k_mm_jobs<<<2 * nbNews + 2 * nbNode, 256, 0, stream>>>(js);
    }
    // L8: both cross1 edge_aggs
    k_edge_agg_w<<<(Nq + NEWSq + 3) / 4, 256, 0, stream>>>(
        mkea(bn_off, bn_src, es_news, ed_node, newsS1, v1, nc1, Nq, 1),
        mkea(bw_off, bw_src, es_node, ed_news, nodeS1, news1, NC1, NEWSq, 1),
        nullptr, nullptr, nullptr);

    // L9: QKV2 (NC1 gather) || GAT2 matmul (nc1)
    {
        MMJobs js;
        js.j[0] = mkjob(NC1, ue2_Wq, qb, nullptr, nullptr, nullptr, nullptr, MH, nbMH, 1);
        js.j[1] = mkjob(NC1, ue2_Wk, kb, nullptr, nullptr, nullptr, nullptr, MH, 2 * nbMH, 1);
        js.j[2] = mkjob(NC1, ue2_Wv, vb, nullptr, nullptr, nullptr, nullptr, MH, 3 * nbMH, 1);
        js.j[3] = mkjob(nc1, g2_W, nodeS1, g2_as, g2_ad, es_node, ed_node, Nq, BIG, 0);
        k_mm_jobs<<<3 * nbMH + nbNode, 256, 0, stream>>>(js);
    }
    // L10: attn2 (+ tail copy)
    k_self_attn<<<Bq, 256, 0, stream>>>(qb, kb, vb, news2, Sq * 128, NC1);
    // L11: edge_agg GAT2
    k_edge_agg_w<<<(Nq + 3) / 4, 256, 0, stream>>>(
        mkea(g_off, g_src, es_node, ed_node, nodeS1, nullptr, v2, Nq, 0), eaNone,
        nullptr, nullptr, nullptr);

    // L12: cross2 matmuls
    {
        MMJobs js;
        js.j[0] = mkjob(news2, cg2_Ws, newsS1, cg2_as, nullptr, es_news, nullptr, NEWSq, nbNews, 0);
        js.j[1] = mkjob(v2,    cg2_Wd, nullptr, cg2_ad, nullptr, ed_node, nullptr, Nq, nbNews + nbNode, 0);
        js.j[2] = mkjob(v2,    cg2_Ws, nodeS1,  cg2_as, nullptr, es_node, nullptr, Nq, nbNews + 2 * nbNode, 0);
        js.j[3] = mkjob(news2, cg2_Wd, nullptr, cg2_ad, nullptr, ed_news, nullptr, NEWSq, BIG, 0);
        k_mm_jobs<<<2 * nbNews + 2 * nbNode, 256, 0, stream>>>(js);
    }
    // L13: both cross2 edge_aggs (+ fused gate)
    k_edge_agg_w<<<(Nq + NEWSq + 3) / 4, 256, 0, stream>>>(
        mkea(bn_off, bn_src, es_news, ed_node, newsS1, v2, nc2, Nq, 1),
        mkea(bw_off, bw_src, es_node, ed_news, nodeS1, news2, NC2, NEWSq, 1),
        gate_W, gate_b, gate);

    // L14: QKV3 (NC2 gather)
    {
        MMJobs js;
        js.j[0] = mkjob(NC2, ue3_Wq, qb, nullptr, nullptr, nullptr, nullptr, MH, nbMH, 1);
        js.j[1] = mkjob(NC2, ue3_Wk, kb, nullptr, nullptr, nullptr, nullptr, MH, 2 * nbMH, 1);
        js.j[2] = mkjob(NC2, ue3_Wv, vb, nullptr, nullptr, nullptr, nullptr, MH, 3 * nbMH, 1);
        js.j[3] = jNone;
        k_mm_jobs<<<3 * nbMH, 256, 0, stream>>>(js);
    }
    // L15: attn3
    k_self_attn<<<Bq, 256, 0, stream>>>(qb, kb, vb, UT3, Hq * 128, nullptr);
    // L16: sa tanh-dot
    k_mm_tanh<<<nbMH, 256, 0, stream>>>(UT3, sa_W, MH, sa_b, sa_v, score_bh);
    // L17: fused final (user_pool + mask_pools + gating)
    k_final_fused<<<Bq * NEG1q, 128, 0, stream>>>(UT3, score_bh, nc2, gate,
        hist_mask, pos_mask, neg_masks, NC2, ww_W, ww_b, out);
}